// Round 11
// baseline (322.012 us; speedup 1.0000x reference)
//
#include <hip/hip_runtime.h>

// SpatialAttention (QKNorm, no 1/sqrt(d)): B=1,T=8,S=1024,HID=1152,H=16,D=72
// Pipeline: cvt x->bf16 (sigma) | W^T bf16 (sigma) | qkv GEMM (256x256 block, 8 waves,
//           phase-split schedule, counted vmcnt, 3-buf gld16) | rmsnorm q,k |
//           flash attn (LDS dbuf, swapped QK^T) | out GEMM (r10 128x128) -> f32
// sigma = swap bits 2<->3 of k within each 16-k block on BOTH operands (k-sum invariant).

typedef __attribute__((ext_vector_type(4))) short s16x4;
typedef __attribute__((ext_vector_type(8))) short s16x8;
typedef __attribute__((ext_vector_type(4))) float f32x4;
typedef __attribute__((ext_vector_type(16))) float f32x16;

__device__ __forceinline__ unsigned short f2b(float x) {
  unsigned u = __float_as_uint(x);
  u += 0x7FFFu + ((u >> 16) & 1u);
  return (unsigned short)(u >> 16);
}
__device__ __forceinline__ float b2f(unsigned short u) {
  return __uint_as_float(((unsigned)u) << 16);
}
__device__ __forceinline__ void gld16(const void* g, void* l) {
  __builtin_amdgcn_global_load_lds(
      (const __attribute__((address_space(1))) void*)g,
      (__attribute__((address_space(3))) void*)l, 16, 0, 0);
}

// ---------------- x -> bf16, sigma k-order ----------------
__global__ __launch_bounds__(256) void cvt_bf16_kernel(const float* __restrict__ in,
                                                       unsigned short* __restrict__ out,
                                                       int n16) {
  int i = blockIdx.x * 256 + threadIdx.x;
  if (i >= n16) return;
  const float4* p = (const float4*)(in + (size_t)i * 16);
  float4 a = p[0], b = p[1], c = p[2], d = p[3];
  s16x8 r0, r1;
  r0[0] = (short)f2b(a.x); r0[1] = (short)f2b(a.y); r0[2] = (short)f2b(a.z); r0[3] = (short)f2b(a.w);
  r0[4] = (short)f2b(c.x); r0[5] = (short)f2b(c.y); r0[6] = (short)f2b(c.z); r0[7] = (short)f2b(c.w);
  r1[0] = (short)f2b(b.x); r1[1] = (short)f2b(b.y); r1[2] = (short)f2b(b.z); r1[3] = (short)f2b(b.w);
  r1[4] = (short)f2b(d.x); r1[5] = (short)f2b(d.y); r1[6] = (short)f2b(d.z); r1[7] = (short)f2b(d.w);
  *(s16x8*)(out + (size_t)i * 16) = r0;
  *(s16x8*)(out + (size_t)i * 16 + 8) = r1;
}

// ---------------- W [K][N] f32 -> WT [N][K] bf16, sigma k-order ----------------
__global__ __launch_bounds__(256) void transpose_cvt_kernel(const float* __restrict__ W,
                                                            unsigned short* __restrict__ WT,
                                                            int K, int N) {
  __shared__ float tile[32][33];
  int n0 = blockIdx.x * 32, k0 = blockIdx.y * 32;
  int tx = threadIdx.x, ty = threadIdx.y;
#pragma unroll
  for (int i = 0; i < 4; i++)
    tile[ty + i * 8][tx] = W[(size_t)(k0 + ty + i * 8) * N + n0 + tx];
  __syncthreads();
  int stx = (tx & 19) | ((tx & 4) << 1) | ((tx & 8) >> 1);  // swap bits 2,3
#pragma unroll
  for (int i = 0; i < 4; i++)
    WT[(size_t)(n0 + ty + i * 8) * K + k0 + stx] = f2b(tile[tx][ty + i * 8]);
}

// ---------------- fused qkv GEMM: [8192,1152] @ [3584,1152]^T (rows>=3456 zero pad) ----------
// 256x256 block, 512 thr / 8 waves (2M x 4N), wave tile 128x64, 32x32x16 MFMA, BK=32.
// 3 LDS bufs x (A 16KB + B 16KB) = 96 KB. Per K-tile two phases:
//   p0: ds_read A(m0,1)+B (8 b128) | stage A-unit of tile t+2 | bar | lgkm0 | 8 MFMA
//   p1: ds_read A(m2,3)   (4 b128) | stage B-unit of tile t+2 | bar | lgkm0 | 8 MFMA
//   boundary: vmcnt(4) (counted: retires exactly tile t+1's units) + bar.
// Chunk swizzle (proven r10): LDS slot j of row r holds global chunk j^((r>>1)&3);
// read slot = (2ks+lh)^((r>>1)&3) -> conflict-free b128.
__global__ __launch_bounds__(512, 2) void gemm_qkv_kernel(const unsigned short* __restrict__ A,
                                                          const unsigned short* __restrict__ BT,
                                                          const float* __restrict__ biasq,
                                                          const float* __restrict__ biaskv,
                                                          unsigned short* __restrict__ qn,
                                                          unsigned short* __restrict__ kn,
                                                          unsigned short* __restrict__ vt) {
  constexpr int K = 1152;
  constexpr int NT = 36;
  __shared__ __align__(16) unsigned short As[3][8192];  // 16 KB per buf: [256 rows][32 k]
  __shared__ __align__(16) unsigned short Bs[3][8192];
  int tid = threadIdx.x;
  int lane = tid & 63, wave = tid >> 6;
  int wm = wave >> 2, wn = wave & 3;
  int wr = wm * 128, wc = wn * 64;
  int l31 = lane & 31, lh = lane >> 5;
  // block map: 448 = 8 xcd x (4 iby x 14 ibx); consecutive w sweep bx (A-tile hot in L2)
  int bid = blockIdx.x;
  int xcd = bid & 7, w = bid >> 3;
  int iby = w / 14, ibx = w - iby * 14;
  int brow = (xcd * 4 + iby) * 256, bcol = ibx * 256;
  // staging: dest chunk d -> row=d>>2, slot j=d&3, src chunk j^((row>>1)&3)
  int d1 = wave * 128 + lane, d2 = d1 + 64;
  int r1 = d1 >> 2, j1 = d1 & 3;
  int r2 = d2 >> 2, j2 = d2 & 3;
  const unsigned short* A1 = A + (size_t)(brow + r1) * K + (j1 ^ ((r1 >> 1) & 3)) * 8;
  const unsigned short* A2 = A + (size_t)(brow + r2) * K + (j2 ^ ((r2 >> 1) & 3)) * 8;
  const unsigned short* B1 = BT + (size_t)(bcol + r1) * K + (j1 ^ ((r1 >> 1) & 3)) * 8;
  const unsigned short* B2 = BT + (size_t)(bcol + r2) * K + (j2 ^ ((r2 >> 1) & 3)) * 8;
  int dstL = wave * 1024, dstH = wave * 1024 + 512;  // u16 offsets (wave-uniform)
#define STAGE_A(KT, BUF) { gld16(A1 + (KT) * 32, &As[BUF][dstL]); gld16(A2 + (KT) * 32, &As[BUF][dstH]); }
#define STAGE_B(KT, BUF) { gld16(B1 + (KT) * 32, &Bs[BUF][dstL]); gld16(B2 + (KT) * 32, &Bs[BUF][dstH]); }
  // fragment-read row/swizzle constants
  int rA[4], fA[4], rB[2], fB[2];
#pragma unroll
  for (int m = 0; m < 4; m++) { rA[m] = wr + m * 32 + l31; fA[m] = (rA[m] >> 1) & 3; }
#pragma unroll
  for (int n = 0; n < 2; n++) { rB[n] = wc + n * 32 + l31; fB[n] = (rB[n] >> 1) & 3; }
  // prologue: tiles 0,1
  STAGE_A(0, 0); STAGE_B(0, 0);
  STAGE_A(1, 1); STAGE_B(1, 1);
  asm volatile("s_waitcnt vmcnt(4)" ::: "memory");
  __builtin_amdgcn_s_barrier();
  f32x16 acc[4][2] = {};
  int cur = 0;
  for (int t = 0; t < NT; t++) {
    int nxt = cur + 2; if (nxt >= 3) nxt -= 3;
    // ---- phase 0: A m=0,1 + B; stage A-unit(t+2)
    s16x8 a0[2][2], b0[2][2];
#pragma unroll
    for (int m = 0; m < 2; m++)
#pragma unroll
      for (int ks = 0; ks < 2; ks++)
        a0[m][ks] = *(const s16x8*)&As[cur][rA[m] * 32 + ((2 * ks + lh) ^ fA[m]) * 8];
#pragma unroll
    for (int n = 0; n < 2; n++)
#pragma unroll
      for (int ks = 0; ks < 2; ks++)
        b0[n][ks] = *(const s16x8*)&Bs[cur][rB[n] * 32 + ((2 * ks + lh) ^ fB[n]) * 8];
    if (t + 2 < NT) STAGE_A(t + 2, nxt);
    __builtin_amdgcn_s_barrier();
    asm volatile("s_waitcnt lgkmcnt(0)" ::: "memory");
    __builtin_amdgcn_sched_barrier(0);
    __builtin_amdgcn_s_setprio(1);
#pragma unroll
    for (int m = 0; m < 2; m++)
#pragma unroll
      for (int n = 0; n < 2; n++)
#pragma unroll
        for (int ks = 0; ks < 2; ks++)
          acc[m][n] = __builtin_amdgcn_mfma_f32_32x32x16_bf16(a0[m][ks], b0[n][ks], acc[m][n], 0, 0, 0);
    __builtin_amdgcn_s_setprio(0);
    // ---- phase 1: A m=2,3 (B reused from regs); stage B-unit(t+2)
    s16x8 a1[2][2];
#pragma unroll
    for (int m = 0; m < 2; m++)
#pragma unroll
      for (int ks = 0; ks < 2; ks++)
        a1[m][ks] = *(const s16x8*)&As[cur][rA[m + 2] * 32 + ((2 * ks + lh) ^ fA[m + 2]) * 8];
    if (t + 2 < NT) STAGE_B(t + 2, nxt);
    __builtin_amdgcn_s_barrier();
    asm volatile("s_waitcnt lgkmcnt(0)" ::: "memory");
    __builtin_amdgcn_sched_barrier(0);
    __builtin_amdgcn_s_setprio(1);
#pragma unroll
    for (int m = 0; m < 2; m++)
#pragma unroll
      for (int n = 0; n < 2; n++)
#pragma unroll
        for (int ks = 0; ks < 2; ks++)
          acc[m + 2][n] = __builtin_amdgcn_mfma_f32_32x32x16_bf16(a1[m][ks], b0[n][ks], acc[m + 2][n], 0, 0, 0);
    __builtin_amdgcn_s_setprio(0);
    // ---- tile boundary: counted wait (tile t+1's units retired), never 0 until tail
    if (t < NT - 1) {
      if (t < NT - 2)
        asm volatile("s_waitcnt vmcnt(4)" ::: "memory");
      else
        asm volatile("s_waitcnt vmcnt(0)" ::: "memory");
      __builtin_amdgcn_s_barrier();
    }
    cur = cur + 1; if (cur >= 3) cur = 0;
  }
#undef STAGE_A
#undef STAGE_B
  // epilogue: C/D 32x32: col = l31, row = (reg&3) + 8*(reg>>2) + 4*lh (col math hoisted)
#pragma unroll
  for (int m = 0; m < 4; m++) {
#pragma unroll
    for (int n = 0; n < 2; n++) {
      int gcol = bcol + wc + n * 32 + l31;
      if (gcol >= 3456) continue;
      float bias = (gcol < 1152) ? biasq[gcol] : biaskv[gcol - 1152];
      int c = (gcol < 1152) ? gcol : (gcol < 2304 ? gcol - 1152 : gcol - 2304);
      int h = c / 72, d = c - h * 72;
      int rowbase = brow + wr + m * 32 + 4 * lh;
#pragma unroll
      for (int reg = 0; reg < 16; reg++) {
        int grow = rowbase + (reg & 3) + 8 * (reg >> 2);
        float v = acc[m][n][reg] + bias;
        int t = grow >> 10, s = grow & 1023;
        if (gcol < 2304) {
          unsigned short* dst = (gcol < 1152) ? qn : kn;
          dst[((size_t)((t * 16 + h) * 1024 + s)) * 96 + d] = f2b(v);
        } else {
          vt[((size_t)((t * 16 + h) * 80 + d)) * 1024 + s] = f2b(v);
        }
      }
    }
  }
}

// ---------------- out GEMM (r10 structure): C[M,N] = A[M,K] @ BT[N,K]^T, f32 out ----------------
__global__ __launch_bounds__(256) void gemm_out_kernel(const unsigned short* __restrict__ A,
                                                       const unsigned short* __restrict__ BT,
                                                       int N, int gx,
                                                       float* __restrict__ outF) {
  constexpr int K = 1152;
  constexpr int NT = K / 32;
  __shared__ __align__(16) unsigned short As[3 * 4096];
  __shared__ __align__(16) unsigned short Bs[3 * 4096];
  int tid = threadIdx.x;
  int lane = tid & 63, wave = tid >> 6;
  int wr = (wave >> 1) * 64, wc = (wave & 1) * 64;
  int l31 = lane & 31, lh = lane >> 5;
  int bid = blockIdx.x;
  int xcd = bid & 7;
  int w = bid >> 3;
  int st = w / 24, inner = w - st * 24;
  int ibx = inner % 3, iby = inner / 3;
  int bx = st * 3 + ibx;
  int by = xcd * 8 + iby;
  int brow = by * 128, bcol = bx * 128;
  const unsigned short* AsrcP[2];
  const unsigned short* BsrcP[2];
  int dst0[2];
#pragma unroll
  for (int i = 0; i < 2; i++) {
    int c = tid + 256 * i;
    int row = c >> 2, j = c & 3;
    int ch = j ^ ((row >> 1) & 3);
    AsrcP[i] = A + (size_t)(brow + row) * K + ch * 8;
    BsrcP[i] = BT + (size_t)(bcol + row) * K + ch * 8;
    dst0[i] = (wave * 64 + 256 * i) * 8;
  }
#define STAGE(KT, BUF)                                          \
  {                                                             \
    int kb = (KT) * 32;                                         \
    gld16(AsrcP[0] + kb, &As[(BUF) * 4096 + dst0[0]]);          \
    gld16(BsrcP[0] + kb, &Bs[(BUF) * 4096 + dst0[0]]);          \
    gld16(AsrcP[1] + kb, &As[(BUF) * 4096 + dst0[1]]);          \
    gld16(BsrcP[1] + kb, &Bs[(BUF) * 4096 + dst0[1]]);          \
  }
  int fr = (l31 >> 1) & 3;
  int slotk[2] = {(lh ^ fr) * 8, ((2 + lh) ^ fr) * 8};
  STAGE(0, 0);
  STAGE(1, 1);
  f32x16 acc[2][2] = {};
  int cur = 0;
  for (int kt = 0; kt < NT; kt++) {
    if (kt < NT - 1)
      asm volatile("s_waitcnt vmcnt(4)\n\ts_barrier" ::: "memory");
    else
      asm volatile("s_waitcnt vmcnt(0)\n\ts_barrier" ::: "memory");
    if (kt + 2 < NT) {
      int nb = (cur == 0) ? 2 : cur - 1;
      STAGE(kt + 2, nb);
    }
    int ab = cur * 4096;
#pragma unroll
    for (int kk = 0; kk < 2; kk++) {
      int so = slotk[kk];
      s16x8 af[2], bf[2];
#pragma unroll
      for (int m = 0; m < 2; m++)
        af[m] = *(const s16x8*)&As[ab + (wr + m * 32 + l31) * 32 + so];
#pragma unroll
      for (int n = 0; n < 2; n++)
        bf[n] = *(const s16x8*)&Bs[ab + (wc + n * 32 + l31) * 32 + so];
      __builtin_amdgcn_s_setprio(1);
#pragma unroll
      for (int m = 0; m < 2; m++)
#pragma unroll
        for (int n = 0; n < 2; n++)
          acc[m][n] = __builtin_amdgcn_mfma_f32_32x32x16_bf16(af[m], bf[n], acc[m][n], 0, 0, 0);
      __builtin_amdgcn_s_setprio(0);
    }
    cur = (cur == 2) ? 0 : cur + 1;
  }
#undef STAGE
#pragma unroll
  for (int m = 0; m < 2; m++) {
#pragma unroll
    for (int n = 0; n < 2; n++) {
#pragma unroll
      for (int reg = 0; reg < 16; reg++) {
        int grow = brow + wr + m * 32 + (reg & 3) + 8 * (reg >> 2) + 4 * lh;
        int gcol = bcol + wc + n * 32 + l31;
        outF[(size_t)grow * N + gcol] = acc[m][n][reg];
      }
    }
  }
}

// ---------------- fused per-(row,head) RMSNorm for q and k, zero-fills pads ----------------
__global__ __launch_bounds__(256) void rmsnorm2_kernel(unsigned short* __restrict__ qn,
                                                       unsigned short* __restrict__ kn,
                                                       const float* __restrict__ qg,
                                                       const float* __restrict__ kg) {
  int r = blockIdx.x * 4 + (threadIdx.x >> 6);
  int isK = r >= 131072;
  int g = isK ? r - 131072 : r;
  unsigned short* buf = isK ? kn : qn;
  const float* gamma = isK ? kg : qg;
  int h = (g >> 10) & 15;
  size_t base = (size_t)g * 96;
  int l = threadIdx.x & 63;
  float e0 = b2f(buf[base + l]);
  float e1 = 0.f;
  if (l < 8) e1 = b2f(buf[base + 64 + l]);
  float ss = e0 * e0 + e1 * e1;
#pragma unroll
  for (int m = 1; m < 64; m <<= 1) ss += __shfl_xor(ss, m);
  float sc = rsqrtf(ss * (1.0f / 72.0f) + 1e-6f);
  buf[base + l] = f2b(e0 * sc * gamma[h * 72 + l]);
  if (l < 32) {
    float v = 0.f;
    if (l < 8) v = e1 * sc * gamma[h * 72 + 64 + l];
    buf[base + 64 + l] = f2b(v);
  }
}

// ---------------- flash attention: LDS dbuf 2-phase, swapped QK^T, P in registers ----------------
__global__ __launch_bounds__(256) void attn_kernel(const unsigned short* __restrict__ Qn,
                                                   const unsigned short* __restrict__ Kn,
                                                   const unsigned short* __restrict__ VtG,
                                                   unsigned short* __restrict__ att) {
  __shared__ unsigned short Kl[2][64][100];
  __shared__ unsigned short Vt[2][80][76];
  int tid = threadIdx.x;
  int lane = tid & 63, wave = tid >> 6;
  int l15 = lane & 15, lq = lane >> 4, kf = lq * 4;
  int bid = blockIdx.x;
  int orig = (bid & 7) * 256 + (bid >> 3);
  int qb = orig & 15, th = orig >> 4;
  int t = th >> 4, h = th & 15;
  const unsigned short* Q = Qn + (size_t)th * 1024 * 96;
  const unsigned short* Kp = Kn + (size_t)th * 1024 * 96;
  const unsigned short* Vg = VtG + (size_t)th * 80 * 1024;
  int qrow0 = qb * 64 + wave * 16;
  int krow[3], kco[3], vd[3], vco[3];
#pragma unroll
  for (int i = 0; i < 3; i++) {
    int c = tid + i * 256;
    krow[i] = c / 12;
    kco[i] = c - 12 * krow[i];
    int cc = tid + i * 256;
    vd[i] = cc >> 3;
    vco[i] = cc & 7;
  }
  bool v2 = tid < 128;
  s16x8 sk[3], sv[3];
  s16x8 qf[3];
#pragma unroll
  for (int c = 0; c < 3; c++) {
    const unsigned short* p = Q + (size_t)(qrow0 + l15) * 96 + c * 32 + kf;
    s16x4 lo = *(const s16x4*)p;
    s16x4 hi = *(const s16x4*)(p + 16);
    qf[c] = __builtin_shufflevector(lo, hi, 0, 1, 2, 3, 4, 5, 6, 7);
  }
  f32x4 o[5] = {};
  float m_r = -3.0e38f, l_r = 0.f;

#pragma unroll
  for (int i = 0; i < 3; i++)
    sk[i] = *(const s16x8*)(Kp + (size_t)krow[i] * 96 + kco[i] * 8);
#pragma unroll
  for (int i = 0; i < 2; i++)
    sv[i] = *(const s16x8*)(Vg + (size_t)vd[i] * 1024 + vco[i] * 8);
  if (v2) sv[2] = *(const s16x8*)(Vg + (size_t)vd[2] * 1024 + vco[2] * 8);
#pragma unroll
  for (int i = 0; i < 3; i++) *(s16x8*)&Kl[0][krow[i]][kco[i] * 8] = sk[i];
#pragma unroll
  for (int i = 0; i < 2; i++) *(s16x8*)&Vt[0][vd[i]][vco[i] * 8] = sv[i];
  if (v2) *(s16x8*)&Vt[0][vd[2]][vco[2] * 8] = sv[2];

  for (int tt = 0; tt < 16; tt++) {
    __syncthreads();
    int cur = tt & 1;
    if (tt < 15) {
      int kv1 = (tt + 1) * 64;
#pragma unroll
      for (int i = 0; i < 3; i++)
        sk[i] = *(const s16x8*)(Kp + (size_t)(kv1 + krow[i]) * 96 + kco[i] * 8);
#pragma unroll
      for (int i = 0; i < 2; i++)
        sv[i] = *(const s16x8*)(Vg + (size_t)vd[i] * 1024 + kv1 + vco[i] * 8);
      if (v2) sv[2] = *(const s16x8*)(Vg + (size_t)vd[2] * 1024 + kv1 + vco[2] * 8);
    }
    f32x4 st[4];
    __builtin_amdgcn_s_setprio(1);
#pragma unroll
    for (int n = 0; n < 4; n++) {
      f32x4 a = {};
#pragma unroll
      for (int c = 0; c < 3; c++) {
        s16x4 lo = *(const s16x4*)&Kl[cur][n * 16 + l15][c * 32 + kf];
        s16x4 hi = *(const s16x4*)&Kl[cur][n * 16 + l15][c * 32 + kf + 16];
        s16x8 kfr = __builtin_shufflevector(lo, hi, 0, 1, 2, 3, 4, 5, 6, 7);
        a = __builtin_amdgcn_mfma_f32_16x16x32_bf16(kfr, qf[c], a, 0, 0, 0);
      }
      st[n] = a;
    }
    __builtin_amdgcn_s_setprio(0);
    float tmax = st[0][0];
#pragma unroll
    for (int n = 0; n < 4; n++)
#pragma unroll
      for (int r = 0; r < 4; r++) tmax = fmaxf(tmax, st[n][r]);
    tmax = fmaxf(tmax, __shfl_xor(tmax, 16));
    tmax = fmaxf(tmax, __shfl_xor(tmax, 32));
    float mn = fmaxf(m_r, tmax);
    float scale = __expf(m_r - mn);
    m_r = mn;
    float sum = 0.f;
#pragma unroll
    for (int n = 0; n < 4; n++)
#pragma unroll
      for (int r = 0; r < 4; r++) {
        float p = __expf(st[n][r] - mn);
        st[n][r] = p;
        sum += p;
      }
    sum += __shfl_xor(sum, 16);
    sum += __shfl_xor(sum, 32);
    l_r = l_r * scale + sum;
#pragma unroll
    for (int r = 0; r < 4; r++) {
      float scq = __shfl(scale, 4 * lq + r);
#pragma unroll
      for (int v = 0; v < 5; v++) o[v][r] *= scq;
    }
    __builtin_amdgcn_s_setprio(1);
#pragma unroll
    for (int b = 0; b < 2; b++) {
      s16x8 pf;
#pragma unroll
      for (int j = 0; j < 8; j++) pf[j] = (short)f2b(st[2 * b + (j >> 2)][j & 3]);
#pragma unroll
      for (int v = 0; v < 5; v++) {
        s16x4 vlo = *(const s16x4*)&Vt[cur][v * 16 + l15][b * 32 + kf];
        s16x4 vhi = *(const s16x4*)&Vt[cur][v * 16 + l15][b * 32 + kf + 16];
        s16x8 vf = __builtin_shufflevector(vlo, vhi, 0, 1, 2, 3, 4, 5, 6, 7);
        o[v] = __builtin_amdgcn_mfma_f32_16x16x32_bf16(pf, vf, o[v], 0, 0, 0);
      }
    }
    __builtin_amdgcn_s_setprio(0);
    if (tt < 15) {
      int nxt = cur ^ 1;
#pragma unroll
      for (int i = 0; i < 3; i++) *(s16x8*)&Kl[nxt][krow[i]][kco[i] * 8] = sk[i];
#pragma unroll
      for (int i = 0; i < 2; i++) *(s16x8*)&Vt[nxt][vd[i]][vco[i] * 8] = sv[i];
      if (v2) *(s16x8*)&Vt[nxt][vd[2]][vco[2] * 8] = sv[2];
    }
  }
#pragma unroll
  for (int r = 0; r < 4; r++) {
    float inv = 1.0f / __shfl(l_r, 4 * lq + r);
    int qrow = qrow0 + 4 * lq + r;
    size_t rowbase = (size_t)(t * 1024 + qrow) * 1152;
#pragma unroll
    for (int v = 0; v < 5; v++) {
      int d = v * 16 + l15;
      if (d < 72) {
        int col = h * 72 + d;
        int scol = (col & ~12) | ((col & 4) << 1) | ((col & 8) >> 1);
        att[rowbase + scol] = f2b(o[v][r] * inv);
      }
    }
  }
}

extern "C" void kernel_launch(void* const* d_in, const int* in_sizes, int n_in,
                              void* d_out, int out_size, void* d_ws, size_t ws_size,
                              hipStream_t stream) {
  const float* x   = (const float*)d_in[0];
  const float* Wq  = (const float*)d_in[1];
  const float* bq  = (const float*)d_in[2];
  const float* Wkv = (const float*)d_in[3];
  const float* bkv = (const float*)d_in[4];
  const float* qg  = (const float*)d_in[5];
  const float* kg  = (const float*)d_in[6];
  const float* Wo  = (const float*)d_in[7];
  float* out = (float*)d_out;

  char* w = (char*)d_ws;
  unsigned short* xb   = (unsigned short*)w; w += (size_t)8192 * 1152 * 2;
  unsigned short* WqT  = (unsigned short*)w; w += (size_t)1152 * 1152 * 2;  // [WqT;WkvT;pad] = [3584][1152]
  unsigned short* WkvT = (unsigned short*)w; w += (size_t)2304 * 1152 * 2;
  unsigned short* Wpad = (unsigned short*)w; w += (size_t)128 * 1152 * 2;   // zeroed pad rows
  unsigned short* WoT  = (unsigned short*)w; w += (size_t)1152 * 1152 * 2;
  unsigned short* qn   = (unsigned short*)w; w += (size_t)128 * 1024 * 96 * 2;
  unsigned short* kn   = (unsigned short*)w; w += (size_t)128 * 1024 * 96 * 2;
  unsigned short* vt   = (unsigned short*)w; w += (size_t)128 * 80 * 1024 * 2;
  unsigned short* att  = (unsigned short*)w; w += (size_t)8192 * 1152 * 2;

  hipMemsetAsync(Wpad, 0, (size_t)128 * 1152 * 2, stream);
  cvt_bf16_kernel<<<2304, 256, 0, stream>>>(x, xb, 9437184 / 16);
  transpose_cvt_kernel<<<dim3(36, 36), dim3(32, 8), 0, stream>>>(Wq, WqT, 1152, 1152);
  transpose_cvt_kernel<<<dim3(72, 36), dim3(32, 8), 0, stream>>>(Wkv, WkvT, 1152, 2304);
  transpose_cvt_kernel<<<dim3(36, 36), dim3(32, 8), 0, stream>>>(Wo, WoT, 1152, 1152);

  // fused q,k,v^T GEMM: BT = [WqT;WkvT;pad] = [3584][1152], grid 32*14=448, 512 thr
  gemm_qkv_kernel<<<448, 512, 0, stream>>>(xb, WqT, bq, bkv, qn, kn, vt);
  rmsnorm2_kernel<<<65536, 256, 0, stream>>>(qn, kn, qg, kg);

  attn_kernel<<<2048, 256, 0, stream>>>(qn, kn, vt, att);

  // out = att @ WoT^T, grid 9*64=576
  gemm_out_kernel<<<576, 256, 0, stream>>>(att, WoT, 1152, 9, out);
}

// Round 12
// 308.755 us; speedup vs baseline: 1.0429x; 1.0429x over previous
//
#include <hip/hip_runtime.h>

// SpatialAttention (QKNorm, no 1/sqrt(d)): B=1,T=8,S=1024,HID=1152,H=16,D=72
// Pipeline: cvt x->bf16 (sigma) | W^T bf16 (sigma) | qkv GEMM (r10: 256x128 block, 128x64
//           wave tile, 32x32x16, BK=32 gld16 3-buf, vmcnt(6)) | rmsnorm q,k |
//           flash attn (128 q-rows/block, 2 groups/wave, LDS dbuf, swapped QK^T) |
//           out GEMM (r10 128x128) -> f32
// sigma = swap bits 2<->3 of k within each 16-k block on BOTH operands (k-sum invariant).

typedef __attribute__((ext_vector_type(4))) short s16x4;
typedef __attribute__((ext_vector_type(8))) short s16x8;
typedef __attribute__((ext_vector_type(4))) float f32x4;
typedef __attribute__((ext_vector_type(16))) float f32x16;

__device__ __forceinline__ unsigned short f2b(float x) {
  unsigned u = __float_as_uint(x);
  u += 0x7FFFu + ((u >> 16) & 1u);
  return (unsigned short)(u >> 16);
}
__device__ __forceinline__ float b2f(unsigned short u) {
  return __uint_as_float(((unsigned)u) << 16);
}
__device__ __forceinline__ void gld16(const void* g, void* l) {
  __builtin_amdgcn_global_load_lds(
      (const __attribute__((address_space(1))) void*)g,
      (__attribute__((address_space(3))) void*)l, 16, 0, 0);
}

// ---------------- x -> bf16, sigma k-order ----------------
__global__ __launch_bounds__(256) void cvt_bf16_kernel(const float* __restrict__ in,
                                                       unsigned short* __restrict__ out,
                                                       int n16) {
  int i = blockIdx.x * 256 + threadIdx.x;
  if (i >= n16) return;
  const float4* p = (const float4*)(in + (size_t)i * 16);
  float4 a = p[0], b = p[1], c = p[2], d = p[3];
  s16x8 r0, r1;
  r0[0] = (short)f2b(a.x); r0[1] = (short)f2b(a.y); r0[2] = (short)f2b(a.z); r0[3] = (short)f2b(a.w);
  r0[4] = (short)f2b(c.x); r0[5] = (short)f2b(c.y); r0[6] = (short)f2b(c.z); r0[7] = (short)f2b(c.w);
  r1[0] = (short)f2b(b.x); r1[1] = (short)f2b(b.y); r1[2] = (short)f2b(b.z); r1[3] = (short)f2b(b.w);
  r1[4] = (short)f2b(d.x); r1[5] = (short)f2b(d.y); r1[6] = (short)f2b(d.z); r1[7] = (short)f2b(d.w);
  *(s16x8*)(out + (size_t)i * 16) = r0;
  *(s16x8*)(out + (size_t)i * 16 + 8) = r1;
}

// ---------------- W [K][N] f32 -> WT [N][K] bf16, sigma k-order ----------------
__global__ __launch_bounds__(256) void transpose_cvt_kernel(const float* __restrict__ W,
                                                            unsigned short* __restrict__ WT,
                                                            int K, int N) {
  __shared__ float tile[32][33];
  int n0 = blockIdx.x * 32, k0 = blockIdx.y * 32;
  int tx = threadIdx.x, ty = threadIdx.y;
#pragma unroll
  for (int i = 0; i < 4; i++)
    tile[ty + i * 8][tx] = W[(size_t)(k0 + ty + i * 8) * N + n0 + tx];
  __syncthreads();
  int stx = (tx & 19) | ((tx & 4) << 1) | ((tx & 8) >> 1);  // swap bits 2,3
#pragma unroll
  for (int i = 0; i < 4; i++)
    WT[(size_t)(n0 + ty + i * 8) * K + k0 + stx] = f2b(tile[tx][ty + i * 8]);
}

// ---------------- fused qkv GEMM (r10): [8192,1152] @ [3456,1152]^T ----------------
__global__ __launch_bounds__(256) void gemm_qkv_kernel(const unsigned short* __restrict__ A,
                                                       const unsigned short* __restrict__ BT,
                                                       const float* __restrict__ biasq,
                                                       const float* __restrict__ biaskv,
                                                       unsigned short* __restrict__ qn,
                                                       unsigned short* __restrict__ kn,
                                                       unsigned short* __restrict__ vt) {
  constexpr int K = 1152;
  constexpr int NT = K / 32;  // 36
  __shared__ __align__(16) unsigned short As[3 * 8192];  // 3 bufs x [256 rows][32 k]
  __shared__ __align__(16) unsigned short Bs[3 * 4096];  // 3 bufs x [128 rows][32 k]
  int tid = threadIdx.x;
  int lane = tid & 63, wave = tid >> 6;
  int wr = (wave >> 1) * 128, wc = (wave & 1) * 64;
  int l31 = lane & 31, lh = lane >> 5;
  int bid = blockIdx.x;
  int xcd = bid & 7;
  int w = bid >> 3;                  // 0..107
  int st = w / 12, inner = w - st * 12;
  int ibx = inner % 3, iby = inner / 3;
  int bx = st * 3 + ibx;             // 0..26
  int by = xcd * 4 + iby;            // 0..31
  int brow = by * 256, bcol = bx * 128;
  const unsigned short* AsrcP[4];
  const unsigned short* BsrcP[2];
  int dstA[4], dstB[2];
#pragma unroll
  for (int i = 0; i < 4; i++) {
    int c = tid + 256 * i;
    int row = c >> 2, j = c & 3;
    AsrcP[i] = A + (size_t)(brow + row) * K + (j ^ ((row >> 1) & 3)) * 8;
    dstA[i] = (wave * 64 + 256 * i) * 8;
  }
#pragma unroll
  for (int i = 0; i < 2; i++) {
    int c = tid + 256 * i;
    int row = c >> 2, j = c & 3;
    BsrcP[i] = BT + (size_t)(bcol + row) * K + (j ^ ((row >> 1) & 3)) * 8;
    dstB[i] = (wave * 64 + 256 * i) * 8;
  }
#define STAGE(KT, BUF)                                           \
  {                                                              \
    int kb = (KT) * 32;                                          \
    gld16(AsrcP[0] + kb, &As[(BUF) * 8192 + dstA[0]]);           \
    gld16(AsrcP[1] + kb, &As[(BUF) * 8192 + dstA[1]]);           \
    gld16(AsrcP[2] + kb, &As[(BUF) * 8192 + dstA[2]]);           \
    gld16(AsrcP[3] + kb, &As[(BUF) * 8192 + dstA[3]]);           \
    gld16(BsrcP[0] + kb, &Bs[(BUF) * 4096 + dstB[0]]);           \
    gld16(BsrcP[1] + kb, &Bs[(BUF) * 4096 + dstB[1]]);           \
  }
  int fr = (l31 >> 1) & 3;
  int slotk[2] = {(lh ^ fr) * 8, ((2 + lh) ^ fr) * 8};
  STAGE(0, 0);
  STAGE(1, 1);
  f32x16 acc[4][2] = {};
  int cur = 0;
  for (int kt = 0; kt < NT; kt++) {
    if (kt < NT - 1)
      asm volatile("s_waitcnt vmcnt(6)\n\ts_barrier" ::: "memory");
    else
      asm volatile("s_waitcnt vmcnt(0)\n\ts_barrier" ::: "memory");
    if (kt + 2 < NT) {
      int nb = (cur == 0) ? 2 : cur - 1;  // (kt+2)%3
      STAGE(kt + 2, nb);
    }
    int ab = cur * 8192, bb = cur * 4096;
#pragma unroll
    for (int kk = 0; kk < 2; kk++) {
      int so = slotk[kk];
      s16x8 af[4], bf[2];
#pragma unroll
      for (int m = 0; m < 4; m++)
        af[m] = *(const s16x8*)&As[ab + (wr + m * 32 + l31) * 32 + so];
#pragma unroll
      for (int n = 0; n < 2; n++)
        bf[n] = *(const s16x8*)&Bs[bb + (wc + n * 32 + l31) * 32 + so];
      __builtin_amdgcn_s_setprio(1);
#pragma unroll
      for (int m = 0; m < 4; m++)
#pragma unroll
        for (int n = 0; n < 2; n++)
          acc[m][n] = __builtin_amdgcn_mfma_f32_32x32x16_bf16(af[m], bf[n], acc[m][n], 0, 0, 0);
      __builtin_amdgcn_s_setprio(0);
    }
    cur = (cur == 2) ? 0 : cur + 1;
  }
#undef STAGE
#pragma unroll
  for (int m = 0; m < 4; m++) {
#pragma unroll
    for (int n = 0; n < 2; n++) {
#pragma unroll
      for (int reg = 0; reg < 16; reg++) {
        int grow = brow + wr + m * 32 + (reg & 3) + 8 * (reg >> 2) + 4 * lh;
        int gcol = bcol + wc + n * 32 + l31;
        float v = acc[m][n][reg];
        v += (gcol < 1152) ? biasq[gcol] : biaskv[gcol - 1152];
        int t = grow >> 10, s = grow & 1023;
        if (gcol < 2304) {
          int c = (gcol < 1152) ? gcol : gcol - 1152;
          int h = c / 72, d = c - h * 72;
          unsigned short* dst = (gcol < 1152) ? qn : kn;
          dst[((size_t)((t * 16 + h) * 1024 + s)) * 96 + d] = f2b(v);
        } else {
          int c = gcol - 2304;
          int h = c / 72, d = c - h * 72;
          vt[((size_t)((t * 16 + h) * 80 + d)) * 1024 + s] = f2b(v);
        }
      }
    }
  }
}

// ---------------- out GEMM (r10 structure): C[M,N] = A[M,K] @ BT[N,K]^T, f32 out ----------------
__global__ __launch_bounds__(256) void gemm_out_kernel(const unsigned short* __restrict__ A,
                                                       const unsigned short* __restrict__ BT,
                                                       int N, int gx,
                                                       float* __restrict__ outF) {
  constexpr int K = 1152;
  constexpr int NT = K / 32;
  __shared__ __align__(16) unsigned short As[3 * 4096];
  __shared__ __align__(16) unsigned short Bs[3 * 4096];
  int tid = threadIdx.x;
  int lane = tid & 63, wave = tid >> 6;
  int wr = (wave >> 1) * 64, wc = (wave & 1) * 64;
  int l31 = lane & 31, lh = lane >> 5;
  int bid = blockIdx.x;
  int xcd = bid & 7;
  int w = bid >> 3;
  int st = w / 24, inner = w - st * 24;
  int ibx = inner % 3, iby = inner / 3;
  int bx = st * 3 + ibx;
  int by = xcd * 8 + iby;
  int brow = by * 128, bcol = bx * 128;
  const unsigned short* AsrcP[2];
  const unsigned short* BsrcP[2];
  int dst0[2];
#pragma unroll
  for (int i = 0; i < 2; i++) {
    int c = tid + 256 * i;
    int row = c >> 2, j = c & 3;
    int ch = j ^ ((row >> 1) & 3);
    AsrcP[i] = A + (size_t)(brow + row) * K + ch * 8;
    BsrcP[i] = BT + (size_t)(bcol + row) * K + ch * 8;
    dst0[i] = (wave * 64 + 256 * i) * 8;
  }
#define STAGE(KT, BUF)                                          \
  {                                                             \
    int kb = (KT) * 32;                                         \
    gld16(AsrcP[0] + kb, &As[(BUF) * 4096 + dst0[0]]);          \
    gld16(BsrcP[0] + kb, &Bs[(BUF) * 4096 + dst0[0]]);          \
    gld16(AsrcP[1] + kb, &As[(BUF) * 4096 + dst0[1]]);          \
    gld16(BsrcP[1] + kb, &Bs[(BUF) * 4096 + dst0[1]]);          \
  }
  int fr = (l31 >> 1) & 3;
  int slotk[2] = {(lh ^ fr) * 8, ((2 + lh) ^ fr) * 8};
  STAGE(0, 0);
  STAGE(1, 1);
  f32x16 acc[2][2] = {};
  int cur = 0;
  for (int kt = 0; kt < NT; kt++) {
    if (kt < NT - 1)
      asm volatile("s_waitcnt vmcnt(4)\n\ts_barrier" ::: "memory");
    else
      asm volatile("s_waitcnt vmcnt(0)\n\ts_barrier" ::: "memory");
    if (kt + 2 < NT) {
      int nb = (cur == 0) ? 2 : cur - 1;
      STAGE(kt + 2, nb);
    }
    int ab = cur * 4096;
#pragma unroll
    for (int kk = 0; kk < 2; kk++) {
      int so = slotk[kk];
      s16x8 af[2], bf[2];
#pragma unroll
      for (int m = 0; m < 2; m++)
        af[m] = *(const s16x8*)&As[ab + (wr + m * 32 + l31) * 32 + so];
#pragma unroll
      for (int n = 0; n < 2; n++)
        bf[n] = *(const s16x8*)&Bs[ab + (wc + n * 32 + l31) * 32 + so];
      __builtin_amdgcn_s_setprio(1);
#pragma unroll
      for (int m = 0; m < 2; m++)
#pragma unroll
        for (int n = 0; n < 2; n++)
          acc[m][n] = __builtin_amdgcn_mfma_f32_32x32x16_bf16(af[m], bf[n], acc[m][n], 0, 0, 0);
      __builtin_amdgcn_s_setprio(0);
    }
    cur = (cur == 2) ? 0 : cur + 1;
  }
#undef STAGE
#pragma unroll
  for (int m = 0; m < 2; m++) {
#pragma unroll
    for (int n = 0; n < 2; n++) {
#pragma unroll
      for (int reg = 0; reg < 16; reg++) {
        int grow = brow + wr + m * 32 + (reg & 3) + 8 * (reg >> 2) + 4 * lh;
        int gcol = bcol + wc + n * 32 + l31;
        outF[(size_t)grow * N + gcol] = acc[m][n][reg];
      }
    }
  }
}

// ---------------- fused per-(row,head) RMSNorm for q and k, zero-fills pads ----------------
__global__ __launch_bounds__(256) void rmsnorm2_kernel(unsigned short* __restrict__ qn,
                                                       unsigned short* __restrict__ kn,
                                                       const float* __restrict__ qg,
                                                       const float* __restrict__ kg) {
  int r = blockIdx.x * 4 + (threadIdx.x >> 6);
  int isK = r >= 131072;
  int g = isK ? r - 131072 : r;
  unsigned short* buf = isK ? kn : qn;
  const float* gamma = isK ? kg : qg;
  int h = (g >> 10) & 15;
  size_t base = (size_t)g * 96;
  int l = threadIdx.x & 63;
  float e0 = b2f(buf[base + l]);
  float e1 = 0.f;
  if (l < 8) e1 = b2f(buf[base + 64 + l]);
  float ss = e0 * e0 + e1 * e1;
#pragma unroll
  for (int m = 1; m < 64; m <<= 1) ss += __shfl_xor(ss, m);
  float sc = rsqrtf(ss * (1.0f / 72.0f) + 1e-6f);
  buf[base + l] = f2b(e0 * sc * gamma[h * 72 + l]);
  if (l < 32) {
    float v = 0.f;
    if (l < 8) v = e1 * sc * gamma[h * 72 + 64 + l];
    buf[base + 64 + l] = f2b(v);
  }
}

// ---------------- flash attention: 128 q-rows/block (2 groups/wave), LDS dbuf,
//                  swapped QK^T, P in registers ----------------
// Qn,Kn: [th][1024][96] bf16 (pads zeroed). VtG: [th][80][1024] bf16. att: sigma cols.
__global__ __launch_bounds__(256) void attn_kernel(const unsigned short* __restrict__ Qn,
                                                   const unsigned short* __restrict__ Kn,
                                                   const unsigned short* __restrict__ VtG,
                                                   unsigned short* __restrict__ att) {
  __shared__ unsigned short Kl[2][64][100];
  __shared__ unsigned short Vt[2][80][76];
  int tid = threadIdx.x;
  int lane = tid & 63, wave = tid >> 6;
  int l15 = lane & 15, lq = lane >> 4, kf = lq * 4;
  // bijective XCD swizzle: nwg=1024 (8 q-blocks x 128 heads)
  int bid = blockIdx.x;
  int orig = (bid & 7) * 128 + (bid >> 3);
  int qb = orig & 7, th = orig >> 3;
  int t = th >> 4, h = th & 15;
  const unsigned short* Q = Qn + (size_t)th * 1024 * 96;
  const unsigned short* Kp = Kn + (size_t)th * 1024 * 96;
  const unsigned short* Vg = VtG + (size_t)th * 80 * 1024;
  int qrow0 = qb * 128 + wave * 32;  // wave owns 32 rows = 2 groups of 16
  int krow[3], kco[3], vd[3], vco[3];
#pragma unroll
  for (int i = 0; i < 3; i++) {
    int c = tid + i * 256;
    krow[i] = c / 12;
    kco[i] = c - 12 * krow[i];
    int cc = tid + i * 256;
    vd[i] = cc >> 3;
    vco[i] = cc & 7;
  }
  bool v2 = tid < 128;
  s16x8 sk[3], sv[3];
  // Q fragments per group (B-operand: col=l15=q, k=d)
  s16x8 qf[2][3];
#pragma unroll
  for (int g = 0; g < 2; g++)
#pragma unroll
    for (int c = 0; c < 3; c++) {
      const unsigned short* p = Q + (size_t)(qrow0 + g * 16 + l15) * 96 + c * 32 + kf;
      s16x4 lo = *(const s16x4*)p;
      s16x4 hi = *(const s16x4*)(p + 16);
      qf[g][c] = __builtin_shufflevector(lo, hi, 0, 1, 2, 3, 4, 5, 6, 7);
    }
  f32x4 o[2][5] = {};
  float m_r[2] = {-3.0e38f, -3.0e38f}, l_r[2] = {0.f, 0.f};

  // prologue: stage tile 0 into buf 0
#pragma unroll
  for (int i = 0; i < 3; i++)
    sk[i] = *(const s16x8*)(Kp + (size_t)krow[i] * 96 + kco[i] * 8);
#pragma unroll
  for (int i = 0; i < 2; i++)
    sv[i] = *(const s16x8*)(Vg + (size_t)vd[i] * 1024 + vco[i] * 8);
  if (v2) sv[2] = *(const s16x8*)(Vg + (size_t)vd[2] * 1024 + vco[2] * 8);
#pragma unroll
  for (int i = 0; i < 3; i++) *(s16x8*)&Kl[0][krow[i]][kco[i] * 8] = sk[i];
#pragma unroll
  for (int i = 0; i < 2; i++) *(s16x8*)&Vt[0][vd[i]][vco[i] * 8] = sv[i];
  if (v2) *(s16x8*)&Vt[0][vd[2]][vco[2] * 8] = sv[2];

  for (int tt = 0; tt < 16; tt++) {
    __syncthreads();
    int cur = tt & 1;
    if (tt < 15) {
      int kv1 = (tt + 1) * 64;
#pragma unroll
      for (int i = 0; i < 3; i++)
        sk[i] = *(const s16x8*)(Kp + (size_t)(kv1 + krow[i]) * 96 + kco[i] * 8);
#pragma unroll
      for (int i = 0; i < 2; i++)
        sv[i] = *(const s16x8*)(Vg + (size_t)vd[i] * 1024 + kv1 + vco[i] * 8);
      if (v2) sv[2] = *(const s16x8*)(Vg + (size_t)vd[2] * 1024 + kv1 + vco[2] * 8);
    }
#pragma unroll
    for (int g = 0; g < 2; g++) {
      // S^T = mfma(K, Q): st[n][r] = S[q=l15][kv = n*16 + 4*lq + r]
      f32x4 st[4];
      __builtin_amdgcn_s_setprio(1);
#pragma unroll
      for (int n = 0; n < 4; n++) {
        f32x4 a = {};
#pragma unroll
        for (int c = 0; c < 3; c++) {
          s16x4 lo = *(const s16x4*)&Kl[cur][n * 16 + l15][c * 32 + kf];
          s16x4 hi = *(const s16x4*)&Kl[cur][n * 16 + l15][c * 32 + kf + 16];
          s16x8 kfr = __builtin_shufflevector(lo, hi, 0, 1, 2, 3, 4, 5, 6, 7);
          a = __builtin_amdgcn_mfma_f32_16x16x32_bf16(kfr, qf[g][c], a, 0, 0, 0);
        }
        st[n] = a;
      }
      __builtin_amdgcn_s_setprio(0);
      // online softmax for q = l15 (16 local + lq-group shfl reduce)
      float tmax = st[0][0];
#pragma unroll
      for (int n = 0; n < 4; n++)
#pragma unroll
        for (int r = 0; r < 4; r++) tmax = fmaxf(tmax, st[n][r]);
      tmax = fmaxf(tmax, __shfl_xor(tmax, 16));
      tmax = fmaxf(tmax, __shfl_xor(tmax, 32));
      float mn = fmaxf(m_r[g], tmax);
      float scale = __expf(m_r[g] - mn);
      m_r[g] = mn;
      float sum = 0.f;
#pragma unroll
      for (int n = 0; n < 4; n++)
#pragma unroll
        for (int r = 0; r < 4; r++) {
          float p = __expf(st[n][r] - mn);
          st[n][r] = p;
          sum += p;
        }
      sum += __shfl_xor(sum, 16);
      sum += __shfl_xor(sum, 32);
      l_r[g] = l_r[g] * scale + sum;
#pragma unroll
      for (int r = 0; r < 4; r++) {
        float scq = __shfl(scale, 4 * lq + r);
#pragma unroll
        for (int v = 0; v < 5; v++) o[g][v][r] *= scq;
      }
      // P fragments directly from st (A-operand: row=l15=q, k=kv)
      __builtin_amdgcn_s_setprio(1);
#pragma unroll
      for (int b = 0; b < 2; b++) {
        s16x8 pf;
#pragma unroll
        for (int j = 0; j < 8; j++) pf[j] = (short)f2b(st[2 * b + (j >> 2)][j & 3]);
#pragma unroll
        for (int v = 0; v < 5; v++) {
          s16x4 vlo = *(const s16x4*)&Vt[cur][v * 16 + l15][b * 32 + kf];
          s16x4 vhi = *(const s16x4*)&Vt[cur][v * 16 + l15][b * 32 + kf + 16];
          s16x8 vf = __builtin_shufflevector(vlo, vhi, 0, 1, 2, 3, 4, 5, 6, 7);
          o[g][v] = __builtin_amdgcn_mfma_f32_16x16x32_bf16(pf, vf, o[g][v], 0, 0, 0);
        }
      }
      __builtin_amdgcn_s_setprio(0);
    }
    // write-late: next tile into the other buffer
    if (tt < 15) {
      int nxt = cur ^ 1;
#pragma unroll
      for (int i = 0; i < 3; i++) *(s16x8*)&Kl[nxt][krow[i]][kco[i] * 8] = sk[i];
#pragma unroll
      for (int i = 0; i < 2; i++) *(s16x8*)&Vt[nxt][vd[i]][vco[i] * 8] = sv[i];
      if (v2) *(s16x8*)&Vt[nxt][vd[2]][vco[2] * 8] = sv[2];
    }
  }
  // epilogue: normalize by l, store d<72 at sigma-permuted column
#pragma unroll
  for (int g = 0; g < 2; g++)
#pragma unroll
    for (int r = 0; r < 4; r++) {
      float inv = 1.0f / __shfl(l_r[g], 4 * lq + r);
      int qrow = qrow0 + g * 16 + 4 * lq + r;
      size_t rowbase = (size_t)(t * 1024 + qrow) * 1152;
#pragma unroll
      for (int v = 0; v < 5; v++) {
        int d = v * 16 + l15;
        if (d < 72) {
          int col = h * 72 + d;
          int scol = (col & ~12) | ((col & 4) << 1) | ((col & 8) >> 1);
          att[rowbase + scol] = f2b(o[g][v][r] * inv);
        }
      }
    }
}

extern "C" void kernel_launch(void* const* d_in, const int* in_sizes, int n_in,
                              void* d_out, int out_size, void* d_ws, size_t ws_size,
                              hipStream_t stream) {
  const float* x   = (const float*)d_in[0];
  const float* Wq  = (const float*)d_in[1];
  const float* bq  = (const float*)d_in[2];
  const float* Wkv = (const float*)d_in[3];
  const float* bkv = (const float*)d_in[4];
  const float* qg  = (const float*)d_in[5];
  const float* kg  = (const float*)d_in[6];
  const float* Wo  = (const float*)d_in[7];
  float* out = (float*)d_out;

  char* w = (char*)d_ws;
  unsigned short* xb   = (unsigned short*)w; w += (size_t)8192 * 1152 * 2;
  unsigned short* WqT  = (unsigned short*)w; w += (size_t)1152 * 1152 * 2;  // contiguous with WkvT
  unsigned short* WkvT = (unsigned short*)w; w += (size_t)2304 * 1152 * 2;
  unsigned short* WoT  = (unsigned short*)w; w += (size_t)1152 * 1152 * 2;
  unsigned short* qn   = (unsigned short*)w; w += (size_t)128 * 1024 * 96 * 2;
  unsigned short* kn   = (unsigned short*)w; w += (size_t)128 * 1024 * 96 * 2;
  unsigned short* vt   = (unsigned short*)w; w += (size_t)128 * 80 * 1024 * 2;
  unsigned short* att  = (unsigned short*)w; w += (size_t)8192 * 1152 * 2;

  cvt_bf16_kernel<<<2304, 256, 0, stream>>>(x, xb, 9437184 / 16);
  transpose_cvt_kernel<<<dim3(36, 36), dim3(32, 8), 0, stream>>>(Wq, WqT, 1152, 1152);
  transpose_cvt_kernel<<<dim3(72, 36), dim3(32, 8), 0, stream>>>(Wkv, WkvT, 1152, 2304);
  transpose_cvt_kernel<<<dim3(36, 36), dim3(32, 8), 0, stream>>>(Wo, WoT, 1152, 1152);

  // fused q,k,v^T GEMM: BT = [WqT ; WkvT] = [3456][1152], grid 32*27=864
  gemm_qkv_kernel<<<864, 256, 0, stream>>>(xb, WqT, bq, bkv, qn, kn, vt);
  rmsnorm2_kernel<<<65536, 256, 0, stream>>>(qn, kn, qg, kg);

  attn_kernel<<<1024, 256, 0, stream>>>(qn, kn, vt, att);

  // out = att @ WoT^T, grid 9*64=576
  gemm_out_kernel<<<576, 256, 0, stream>>>(att, WoT, 1152, 9, out);
}

// Round 14
// 305.229 us; speedup vs baseline: 1.0550x; 1.0116x over previous
//
#include <hip/hip_runtime.h>

// SpatialAttention (QKNorm, no 1/sqrt(d)): B=1,T=8,S=1024,HID=1152,H=16,D=72
// Pipeline: cvt x->bf16 (sigma) | W^T bf16 (sigma) | qkv GEMM (r10 + LDS-transposed vt
//           epilogue) | rmsnorm q,k | flash attn (2 groups, fused QK, SM/PV pipelined,
//           ALWAYS-rescale softmax) | out GEMM (r10 128x128) -> f32
// sigma = swap bits 2<->3 of k within each 16-k block on BOTH operands (k-sum invariant).

typedef __attribute__((ext_vector_type(4))) short s16x4;
typedef __attribute__((ext_vector_type(8))) short s16x8;
typedef __attribute__((ext_vector_type(4))) float f32x4;
typedef __attribute__((ext_vector_type(16))) float f32x16;

__device__ __forceinline__ unsigned short f2b(float x) {
  unsigned u = __float_as_uint(x);
  u += 0x7FFFu + ((u >> 16) & 1u);
  return (unsigned short)(u >> 16);
}
__device__ __forceinline__ float b2f(unsigned short u) {
  return __uint_as_float(((unsigned)u) << 16);
}
__device__ __forceinline__ void gld16(const void* g, void* l) {
  __builtin_amdgcn_global_load_lds(
      (const __attribute__((address_space(1))) void*)g,
      (__attribute__((address_space(3))) void*)l, 16, 0, 0);
}

// ---------------- x -> bf16, sigma k-order ----------------
__global__ __launch_bounds__(256) void cvt_bf16_kernel(const float* __restrict__ in,
                                                       unsigned short* __restrict__ out,
                                                       int n16) {
  int i = blockIdx.x * 256 + threadIdx.x;
  if (i >= n16) return;
  const float4* p = (const float4*)(in + (size_t)i * 16);
  float4 a = p[0], b = p[1], c = p[2], d = p[3];
  s16x8 r0, r1;
  r0[0] = (short)f2b(a.x); r0[1] = (short)f2b(a.y); r0[2] = (short)f2b(a.z); r0[3] = (short)f2b(a.w);
  r0[4] = (short)f2b(c.x); r0[5] = (short)f2b(c.y); r0[6] = (short)f2b(c.z); r0[7] = (short)f2b(c.w);
  r1[0] = (short)f2b(b.x); r1[1] = (short)f2b(b.y); r1[2] = (short)f2b(b.z); r1[3] = (short)f2b(b.w);
  r1[4] = (short)f2b(d.x); r1[5] = (short)f2b(d.y); r1[6] = (short)f2b(d.z); r1[7] = (short)f2b(d.w);
  *(s16x8*)(out + (size_t)i * 16) = r0;
  *(s16x8*)(out + (size_t)i * 16 + 8) = r1;
}

// ---------------- W [K][N] f32 -> WT [N][K] bf16, sigma k-order ----------------
__global__ __launch_bounds__(256) void transpose_cvt_kernel(const float* __restrict__ W,
                                                            unsigned short* __restrict__ WT,
                                                            int K, int N) {
  __shared__ float tile[32][33];
  int n0 = blockIdx.x * 32, k0 = blockIdx.y * 32;
  int tx = threadIdx.x, ty = threadIdx.y;
#pragma unroll
  for (int i = 0; i < 4; i++)
    tile[ty + i * 8][tx] = W[(size_t)(k0 + ty + i * 8) * N + n0 + tx];
  __syncthreads();
  int stx = (tx & 19) | ((tx & 4) << 1) | ((tx & 8) >> 1);  // swap bits 2,3
#pragma unroll
  for (int i = 0; i < 4; i++)
    WT[(size_t)(n0 + ty + i * 8) * K + k0 + stx] = f2b(tile[tx][ty + i * 8]);
}

// ---------------- fused qkv GEMM (r10): [8192,1152] @ [3456,1152]^T ----------------
// vt blocks (bcol>=2304) route C through an LDS [128][264] transpose -> coalesced stores.
__global__ __launch_bounds__(256) void gemm_qkv_kernel(const unsigned short* __restrict__ A,
                                                       const unsigned short* __restrict__ BT,
                                                       const float* __restrict__ biasq,
                                                       const float* __restrict__ biaskv,
                                                       unsigned short* __restrict__ qn,
                                                       unsigned short* __restrict__ kn,
                                                       unsigned short* __restrict__ vt) {
  constexpr int K = 1152;
  constexpr int NT = K / 32;  // 36
  __shared__ __align__(16) unsigned short LDSU[3 * 8192 + 3 * 4096];  // 72 KB
  unsigned short* As = LDSU;            // 3 bufs x [256 rows][32 k]
  unsigned short* Bs = LDSU + 3 * 8192; // 3 bufs x [128 rows][32 k]
  int tid = threadIdx.x;
  int lane = tid & 63, wave = tid >> 6;
  int wr = (wave >> 1) * 128, wc = (wave & 1) * 64;
  int l31 = lane & 31, lh = lane >> 5;
  int bid = blockIdx.x;
  int xcd = bid & 7;
  int w = bid >> 3;                  // 0..107
  int st = w / 12, inner = w - st * 12;
  int ibx = inner % 3, iby = inner / 3;
  int bx = st * 3 + ibx;             // 0..26
  int by = xcd * 4 + iby;            // 0..31
  int brow = by * 256, bcol = bx * 128;
  const unsigned short* AsrcP[4];
  const unsigned short* BsrcP[2];
  int dstA[4], dstB[2];
#pragma unroll
  for (int i = 0; i < 4; i++) {
    int c = tid + 256 * i;
    int row = c >> 2, j = c & 3;
    AsrcP[i] = A + (size_t)(brow + row) * K + (j ^ ((row >> 1) & 3)) * 8;
    dstA[i] = (wave * 64 + 256 * i) * 8;
  }
#pragma unroll
  for (int i = 0; i < 2; i++) {
    int c = tid + 256 * i;
    int row = c >> 2, j = c & 3;
    BsrcP[i] = BT + (size_t)(bcol + row) * K + (j ^ ((row >> 1) & 3)) * 8;
    dstB[i] = (wave * 64 + 256 * i) * 8;
  }
#define STAGE(KT, BUF)                                           \
  {                                                              \
    int kb = (KT) * 32;                                          \
    gld16(AsrcP[0] + kb, &As[(BUF) * 8192 + dstA[0]]);           \
    gld16(AsrcP[1] + kb, &As[(BUF) * 8192 + dstA[1]]);           \
    gld16(AsrcP[2] + kb, &As[(BUF) * 8192 + dstA[2]]);           \
    gld16(AsrcP[3] + kb, &As[(BUF) * 8192 + dstA[3]]);           \
    gld16(BsrcP[0] + kb, &Bs[(BUF) * 4096 + dstB[0]]);           \
    gld16(BsrcP[1] + kb, &Bs[(BUF) * 4096 + dstB[1]]);           \
  }
  int fr = (l31 >> 1) & 3;
  int slotk[2] = {(lh ^ fr) * 8, ((2 + lh) ^ fr) * 8};
  STAGE(0, 0);
  STAGE(1, 1);
  f32x16 acc[4][2] = {};
  int cur = 0;
  for (int kt = 0; kt < NT; kt++) {
    if (kt < NT - 1)
      asm volatile("s_waitcnt vmcnt(6)\n\ts_barrier" ::: "memory");
    else
      asm volatile("s_waitcnt vmcnt(0)\n\ts_barrier" ::: "memory");
    if (kt + 2 < NT) {
      int nb = (cur == 0) ? 2 : cur - 1;  // (kt+2)%3
      STAGE(kt + 2, nb);
    }
    int ab = cur * 8192, bb = cur * 4096;
#pragma unroll
    for (int kk = 0; kk < 2; kk++) {
      int so = slotk[kk];
      s16x8 af[4], bf[2];
#pragma unroll
      for (int m = 0; m < 4; m++)
        af[m] = *(const s16x8*)&As[ab + (wr + m * 32 + l31) * 32 + so];
#pragma unroll
      for (int n = 0; n < 2; n++)
        bf[n] = *(const s16x8*)&Bs[bb + (wc + n * 32 + l31) * 32 + so];
      __builtin_amdgcn_s_setprio(1);
#pragma unroll
      for (int m = 0; m < 4; m++)
#pragma unroll
        for (int n = 0; n < 2; n++)
          acc[m][n] = __builtin_amdgcn_mfma_f32_32x32x16_bf16(af[m], bf[n], acc[m][n], 0, 0, 0);
      __builtin_amdgcn_s_setprio(0);
    }
    cur = (cur == 2) ? 0 : cur + 1;
  }
#undef STAGE
  if (bcol >= 2304) {
    // ---- vt tile: transpose through LDS, coalesced 16B stores ----
    __syncthreads();  // K-loop LDS reads done
    int c0 = bcol - 2304;
#pragma unroll
    for (int m = 0; m < 4; m++) {
#pragma unroll
      for (int n = 0; n < 2; n++) {
        int col = wc + n * 32 + l31;
        float bias = biaskv[1152 + c0 + col];
#pragma unroll
        for (int reg = 0; reg < 16; reg++) {
          int row = wr + m * 32 + (reg & 3) + 8 * (reg >> 2) + 4 * lh;
          LDSU[col * 264 + row] = f2b(acc[m][n][reg] + bias);
        }
      }
    }
    __syncthreads();
    int t = brow >> 10, sbase = brow & 1023;
#pragma unroll
    for (int i = 0; i < 16; i++) {
      int id = tid + 256 * i;
      int col = id >> 5, rowc = id & 31;
      int c = c0 + col;
      int h = c / 72, d = c - h * 72;
      s16x8 v8 = *(const s16x8*)&LDSU[col * 264 + rowc * 8];
      *(s16x8*)(vt + ((size_t)((t * 16 + h) * 80 + d)) * 1024 + sbase + rowc * 8) = v8;
    }
  } else {
    // ---- qn/kn tile: direct stores ----
#pragma unroll
    for (int m = 0; m < 4; m++) {
#pragma unroll
      for (int n = 0; n < 2; n++) {
        int gcol = bcol + wc + n * 32 + l31;
        float bias = (gcol < 1152) ? biasq[gcol] : biaskv[gcol - 1152];
        int c = (gcol < 1152) ? gcol : gcol - 1152;
        int h = c / 72, d = c - h * 72;
        unsigned short* dst = (gcol < 1152) ? qn : kn;
#pragma unroll
        for (int reg = 0; reg < 16; reg++) {
          int grow = brow + wr + m * 32 + (reg & 3) + 8 * (reg >> 2) + 4 * lh;
          float v = acc[m][n][reg] + bias;
          int t = grow >> 10, s = grow & 1023;
          dst[((size_t)((t * 16 + h) * 1024 + s)) * 96 + d] = f2b(v);
        }
      }
    }
  }
}

// ---------------- out GEMM (r10 structure): C[M,N] = A[M,K] @ BT[N,K]^T, f32 out ----------------
__global__ __launch_bounds__(256) void gemm_out_kernel(const unsigned short* __restrict__ A,
                                                       const unsigned short* __restrict__ BT,
                                                       int N, int gx,
                                                       float* __restrict__ outF) {
  constexpr int K = 1152;
  constexpr int NT = K / 32;
  __shared__ __align__(16) unsigned short As[3 * 4096];
  __shared__ __align__(16) unsigned short Bs[3 * 4096];
  int tid = threadIdx.x;
  int lane = tid & 63, wave = tid >> 6;
  int wr = (wave >> 1) * 64, wc = (wave & 1) * 64;
  int l31 = lane & 31, lh = lane >> 5;
  int bid = blockIdx.x;
  int xcd = bid & 7;
  int w = bid >> 3;
  int st = w / 24, inner = w - st * 24;
  int ibx = inner % 3, iby = inner / 3;
  int bx = st * 3 + ibx;
  int by = xcd * 8 + iby;
  int brow = by * 128, bcol = bx * 128;
  const unsigned short* AsrcP[2];
  const unsigned short* BsrcP[2];
  int dst0[2];
#pragma unroll
  for (int i = 0; i < 2; i++) {
    int c = tid + 256 * i;
    int row = c >> 2, j = c & 3;
    int ch = j ^ ((row >> 1) & 3);
    AsrcP[i] = A + (size_t)(brow + row) * K + ch * 8;
    BsrcP[i] = BT + (size_t)(bcol + row) * K + ch * 8;
    dst0[i] = (wave * 64 + 256 * i) * 8;
  }
#define STAGE(KT, BUF)                                          \
  {                                                             \
    int kb = (KT) * 32;                                         \
    gld16(AsrcP[0] + kb, &As[(BUF) * 4096 + dst0[0]]);          \
    gld16(BsrcP[0] + kb, &Bs[(BUF) * 4096 + dst0[0]]);          \
    gld16(AsrcP[1] + kb, &As[(BUF) * 4096 + dst0[1]]);          \
    gld16(BsrcP[1] + kb, &Bs[(BUF) * 4096 + dst0[1]]);          \
  }
  int fr = (l31 >> 1) & 3;
  int slotk[2] = {(lh ^ fr) * 8, ((2 + lh) ^ fr) * 8};
  STAGE(0, 0);
  STAGE(1, 1);
  f32x16 acc[2][2] = {};
  int cur = 0;
  for (int kt = 0; kt < NT; kt++) {
    if (kt < NT - 1)
      asm volatile("s_waitcnt vmcnt(4)\n\ts_barrier" ::: "memory");
    else
      asm volatile("s_waitcnt vmcnt(0)\n\ts_barrier" ::: "memory");
    if (kt + 2 < NT) {
      int nb = (cur == 0) ? 2 : cur - 1;
      STAGE(kt + 2, nb);
    }
    int ab = cur * 4096;
#pragma unroll
    for (int kk = 0; kk < 2; kk++) {
      int so = slotk[kk];
      s16x8 af[2], bf[2];
#pragma unroll
      for (int m = 0; m < 2; m++)
        af[m] = *(const s16x8*)&As[ab + (wr + m * 32 + l31) * 32 + so];
#pragma unroll
      for (int n = 0; n < 2; n++)
        bf[n] = *(const s16x8*)&Bs[ab + (wc + n * 32 + l31) * 32 + so];
      __builtin_amdgcn_s_setprio(1);
#pragma unroll
      for (int m = 0; m < 2; m++)
#pragma unroll
        for (int n = 0; n < 2; n++)
          acc[m][n] = __builtin_amdgcn_mfma_f32_32x32x16_bf16(af[m], bf[n], acc[m][n], 0, 0, 0);
      __builtin_amdgcn_s_setprio(0);
    }
    cur = (cur == 2) ? 0 : cur + 1;
  }
#undef STAGE
#pragma unroll
  for (int m = 0; m < 2; m++) {
#pragma unroll
    for (int n = 0; n < 2; n++) {
#pragma unroll
      for (int reg = 0; reg < 16; reg++) {
        int grow = brow + wr + m * 32 + (reg & 3) + 8 * (reg >> 2) + 4 * lh;
        int gcol = bcol + wc + n * 32 + l31;
        outF[(size_t)grow * N + gcol] = acc[m][n][reg];
      }
    }
  }
}

// ---------------- fused per-(row,head) RMSNorm for q and k, zero-fills pads ----------------
__global__ __launch_bounds__(256) void rmsnorm2_kernel(unsigned short* __restrict__ qn,
                                                       unsigned short* __restrict__ kn,
                                                       const float* __restrict__ qg,
                                                       const float* __restrict__ kg) {
  int r = blockIdx.x * 4 + (threadIdx.x >> 6);
  int isK = r >= 131072;
  int g = isK ? r - 131072 : r;
  unsigned short* buf = isK ? kn : qn;
  const float* gamma = isK ? kg : qg;
  int h = (g >> 10) & 15;
  size_t base = (size_t)g * 96;
  int l = threadIdx.x & 63;
  float e0 = b2f(buf[base + l]);
  float e1 = 0.f;
  if (l < 8) e1 = b2f(buf[base + 64 + l]);
  float ss = e0 * e0 + e1 * e1;
#pragma unroll
  for (int m = 1; m < 64; m <<= 1) ss += __shfl_xor(ss, m);
  float sc = rsqrtf(ss * (1.0f / 72.0f) + 1e-6f);
  buf[base + l] = f2b(e0 * sc * gamma[h * 72 + l]);
  if (l < 32) {
    float v = 0.f;
    if (l < 8) v = e1 * sc * gamma[h * 72 + 64 + l];
    buf[base + 64 + l] = f2b(v);
  }
}

// ---------------- flash attention: 128 q-rows/block, fused-QK both groups,
//                  SM/PV pipelined, ALWAYS-rescale softmax ----------------
__global__ __launch_bounds__(256) void attn_kernel(const unsigned short* __restrict__ Qn,
                                                   const unsigned short* __restrict__ Kn,
                                                   const unsigned short* __restrict__ VtG,
                                                   unsigned short* __restrict__ att) {
  __shared__ unsigned short Kl[2][64][100];
  __shared__ unsigned short Vt[2][80][76];
  int tid = threadIdx.x;
  int lane = tid & 63, wave = tid >> 6;
  int l15 = lane & 15, lq = lane >> 4, kf = lq * 4;
  int bid = blockIdx.x;
  int orig = (bid & 7) * 128 + (bid >> 3);
  int qb = orig & 7, th = orig >> 3;
  int t = th >> 4, h = th & 15;
  const unsigned short* Q = Qn + (size_t)th * 1024 * 96;
  const unsigned short* Kp = Kn + (size_t)th * 1024 * 96;
  const unsigned short* Vg = VtG + (size_t)th * 80 * 1024;
  int qrow0 = qb * 128 + wave * 32;
  int krow[3], kco[3], vd[3], vco[3];
#pragma unroll
  for (int i = 0; i < 3; i++) {
    int c = tid + i * 256;
    krow[i] = c / 12;
    kco[i] = c - 12 * krow[i];
    int cc = tid + i * 256;
    vd[i] = cc >> 3;
    vco[i] = cc & 7;
  }
  bool v2 = tid < 128;
  s16x8 sk[3], sv[3];
  s16x8 qf0[3], qf1[3];
#pragma unroll
  for (int c = 0; c < 3; c++) {
    const unsigned short* p0 = Q + (size_t)(qrow0 + l15) * 96 + c * 32 + kf;
    s16x4 lo = *(const s16x4*)p0;
    s16x4 hi = *(const s16x4*)(p0 + 16);
    qf0[c] = __builtin_shufflevector(lo, hi, 0, 1, 2, 3, 4, 5, 6, 7);
    const unsigned short* p1 = Q + (size_t)(qrow0 + 16 + l15) * 96 + c * 32 + kf;
    s16x4 lo1 = *(const s16x4*)p1;
    s16x4 hi1 = *(const s16x4*)(p1 + 16);
    qf1[c] = __builtin_shufflevector(lo1, hi1, 0, 1, 2, 3, 4, 5, 6, 7);
  }
  f32x4 o[2][5] = {};
  float m_r[2] = {-3.0e38f, -3.0e38f}, l_r[2] = {0.f, 0.f};

#pragma unroll
  for (int i = 0; i < 3; i++)
    sk[i] = *(const s16x8*)(Kp + (size_t)krow[i] * 96 + kco[i] * 8);
#pragma unroll
  for (int i = 0; i < 2; i++)
    sv[i] = *(const s16x8*)(Vg + (size_t)vd[i] * 1024 + vco[i] * 8);
  if (v2) sv[2] = *(const s16x8*)(Vg + (size_t)vd[2] * 1024 + vco[2] * 8);
#pragma unroll
  for (int i = 0; i < 3; i++) *(s16x8*)&Kl[0][krow[i]][kco[i] * 8] = sk[i];
#pragma unroll
  for (int i = 0; i < 2; i++) *(s16x8*)&Vt[0][vd[i]][vco[i] * 8] = sv[i];
  if (v2) *(s16x8*)&Vt[0][vd[2]][vco[2] * 8] = sv[2];

  for (int tt = 0; tt < 16; tt++) {
    __syncthreads();
    int cur = tt & 1;
    if (tt < 15) {
      int kv1 = (tt + 1) * 64;
#pragma unroll
      for (int i = 0; i < 3; i++)
        sk[i] = *(const s16x8*)(Kp + (size_t)(kv1 + krow[i]) * 96 + kco[i] * 8);
#pragma unroll
      for (int i = 0; i < 2; i++)
        sv[i] = *(const s16x8*)(Vg + (size_t)vd[i] * 1024 + kv1 + vco[i] * 8);
      if (v2) sv[2] = *(const s16x8*)(Vg + (size_t)vd[2] * 1024 + kv1 + vco[2] * 8);
    }
    // ---- QK^T for BOTH groups, sharing K-fragment reads ----
    f32x4 st0[4], st1[4];
    __builtin_amdgcn_s_setprio(1);
#pragma unroll
    for (int n = 0; n < 4; n++) {
      f32x4 a0 = {}, a1 = {};
#pragma unroll
      for (int c = 0; c < 3; c++) {
        s16x4 lo = *(const s16x4*)&Kl[cur][n * 16 + l15][c * 32 + kf];
        s16x4 hi = *(const s16x4*)&Kl[cur][n * 16 + l15][c * 32 + kf + 16];
        s16x8 kfr = __builtin_shufflevector(lo, hi, 0, 1, 2, 3, 4, 5, 6, 7);
        a0 = __builtin_amdgcn_mfma_f32_16x16x32_bf16(kfr, qf0[c], a0, 0, 0, 0);
        a1 = __builtin_amdgcn_mfma_f32_16x16x32_bf16(kfr, qf1[c], a1, 0, 0, 0);
      }
      st0[n] = a0;
      st1[n] = a1;
    }
    __builtin_amdgcn_s_setprio(0);
#define SOFTMAX(ST, G)                                                        \
    {                                                                         \
      float tmax = ST[0][0];                                                  \
      _Pragma("unroll") for (int n = 0; n < 4; n++)                           \
        _Pragma("unroll") for (int r = 0; r < 4; r++)                         \
          tmax = fmaxf(tmax, ST[n][r]);                                       \
      tmax = fmaxf(tmax, __shfl_xor(tmax, 16));                               \
      tmax = fmaxf(tmax, __shfl_xor(tmax, 32));                               \
      float mn = fmaxf(m_r[G], tmax);                                         \
      float scale = __expf(m_r[G] - mn);                                      \
      m_r[G] = mn;                                                            \
      float sum = 0.f;                                                        \
      _Pragma("unroll") for (int n = 0; n < 4; n++)                           \
        _Pragma("unroll") for (int r = 0; r < 4; r++) {                       \
          float p = __expf(ST[n][r] - mn);                                    \
          ST[n][r] = p;                                                       \
          sum += p;                                                           \
        }                                                                     \
      sum += __shfl_xor(sum, 16);                                             \
      sum += __shfl_xor(sum, 32);                                             \
      l_r[G] = l_r[G] * scale + sum;                                          \
      _Pragma("unroll") for (int r = 0; r < 4; r++) {                         \
        float scq = __shfl(scale, 4 * lq + r);                                \
        _Pragma("unroll") for (int v = 0; v < 5; v++) o[G][v][r] *= scq;      \
      }                                                                       \
    }
#define PV(ST, G)                                                             \
    {                                                                         \
      __builtin_amdgcn_s_setprio(1);                                          \
      _Pragma("unroll") for (int b = 0; b < 2; b++) {                         \
        s16x8 pf;                                                             \
        _Pragma("unroll") for (int j = 0; j < 8; j++)                         \
          pf[j] = (short)f2b(ST[2 * b + (j >> 2)][j & 3]);                    \
        _Pragma("unroll") for (int v = 0; v < 5; v++) {                       \
          s16x4 vlo = *(const s16x4*)&Vt[cur][v * 16 + l15][b * 32 + kf];     \
          s16x4 vhi = *(const s16x4*)&Vt[cur][v * 16 + l15][b * 32 + kf + 16];\
          s16x8 vf = __builtin_shufflevector(vlo, vhi, 0, 1, 2, 3, 4, 5, 6, 7);\
          o[G][v] = __builtin_amdgcn_mfma_f32_16x16x32_bf16(pf, vf, o[G][v], 0, 0, 0); \
        }                                                                     \
      }                                                                       \
      __builtin_amdgcn_s_setprio(0);                                          \
    }
    SOFTMAX(st0, 0);
    PV(st0, 0);       // PV0 MFMAs overlap SM1's VALU below
    SOFTMAX(st1, 1);
    PV(st1, 1);
#undef SOFTMAX
#undef PV
    if (tt < 15) {
      int nxt = cur ^ 1;
#pragma unroll
      for (int i = 0; i < 3; i++) *(s16x8*)&Kl[nxt][krow[i]][kco[i] * 8] = sk[i];
#pragma unroll
      for (int i = 0; i < 2; i++) *(s16x8*)&Vt[nxt][vd[i]][vco[i] * 8] = sv[i];
      if (v2) *(s16x8*)&Vt[nxt][vd[2]][vco[2] * 8] = sv[2];
    }
  }
  // epilogue: normalize by l, store d<72 at sigma-permuted column
#pragma unroll
  for (int g = 0; g < 2; g++)
#pragma unroll
    for (int r = 0; r < 4; r++) {
      float inv = 1.0f / __shfl(l_r[g], 4 * lq + r);
      int qrow = qrow0 + g * 16 + 4 * lq + r;
      size_t rowbase = (size_t)(t * 1024 + qrow) * 1152;
#pragma unroll
      for (int v = 0; v < 5; v++) {
        int d = v * 16 + l15;
        if (d < 72) {
          int col = h * 72 + d;
          int scol = (col & ~12) | ((col & 4) << 1) | ((col & 8) >> 1);
          att[rowbase + scol] = f2b(o[g][v][r] * inv);
        }
      }
    }
}

extern "C" void kernel_launch(void* const* d_in, const int* in_sizes, int n_in,
                              void* d_out, int out_size, void* d_ws, size_t ws_size,
                              hipStream_t stream) {
  const float* x   = (const float*)d_in[0];
  const float* Wq  = (const float*)d_in[1];
  const float* bq  = (const float*)d_in[2];
  const float* Wkv = (const float*)d_in[3];
  const float* bkv = (const float*)d_in[4];
  const float* qg  = (const float*)d_in[5];
  const float* kg  = (const float*)d_in[6];
  const float* Wo  = (const float*)d_in[7];
  float* out = (float*)d_out;

  char* w = (char*)d_ws;
  unsigned short* xb   = (unsigned short*)w; w += (size_t)8192 * 1152 * 2;
  unsigned short* WqT  = (unsigned short*)w; w += (size_t)1152 * 1152 * 2;  // contiguous with WkvT
  unsigned short* WkvT = (unsigned short*)w; w += (size_t)2304 * 1152 * 2;
  unsigned short* WoT  = (unsigned short*)w; w += (size_t)1152 * 1152 * 2;
  unsigned short* qn   = (unsigned short*)w; w += (size_t)128 * 1024 * 96 * 2;
  unsigned short* kn   = (unsigned short*)w; w += (size_t)128 * 1024 * 96 * 2;
  unsigned short* vt   = (unsigned short*)w; w += (size_t)128 * 80 * 1024 * 2;
  unsigned short* att  = (unsigned short*)w; w += (size_t)8192 * 1152 * 2;

  cvt_bf16_kernel<<<2304, 256, 0, stream>>>(x, xb, 9437184 / 16);
  transpose_cvt_kernel<<<dim3(36, 36), dim3(32, 8), 0, stream>>>(Wq, WqT, 1152, 1152);
  transpose_cvt_kernel<<<dim3(72, 36), dim3(32, 8), 0, stream>>>(Wkv, WkvT, 1152, 2304);
  transpose_cvt_kernel<<<dim3(36, 36), dim3(32, 8), 0, stream>>>(Wo, WoT, 1152, 1152);

  // fused q,k,v^T GEMM: BT = [WqT ; WkvT] = [3456][1152], grid 32*27=864
  gemm_qkv_kernel<<<864, 256, 0, stream>>>(xb, WqT, bq, bkv, qn, kn, vt);
  rmsnorm2_kernel<<<65536, 256, 0, stream>>>(qn, kn, qg, kg);

  attn_kernel<<<1024, 256, 0, stream>>>(qn, kn, vt, att);

  // out = att @ WoT^T, grid 9*64=576
  gemm_out_kernel<<<576, 256, 0, stream>>>(att, WoT, 1152, 9, out);
}

// Round 15
// 302.090 us; speedup vs baseline: 1.0660x; 1.0104x over previous
//
#include <hip/hip_runtime.h>

// SpatialAttention (QKNorm, no 1/sqrt(d)): B=1,T=8,S=1024,HID=1152,H=16,D=72
// Pipeline: cvt x->bf16 (sigma) | W^T bf16 (sigma) | qkv GEMM (r10 + LDS-transposed vt
//           epilogue) | rmsnorm q,k | flash attn (2 groups, fused QK, SM/PV pipelined,
//           cvt_pk P-conversion) | out GEMM (r10 128x128) -> f32
// sigma = swap bits 2<->3 of k within each 16-k block on BOTH operands (k-sum invariant).

typedef __attribute__((ext_vector_type(4))) short s16x4;
typedef __attribute__((ext_vector_type(8))) short s16x8;
typedef __attribute__((ext_vector_type(4))) float f32x4;
typedef __attribute__((ext_vector_type(16))) float f32x16;
typedef __attribute__((ext_vector_type(4))) int i32x4;

__device__ __forceinline__ unsigned short f2b(float x) {
  unsigned u = __float_as_uint(x);
  u += 0x7FFFu + ((u >> 16) & 1u);
  return (unsigned short)(u >> 16);
}
__device__ __forceinline__ float b2f(unsigned short u) {
  return __uint_as_float(((unsigned)u) << 16);
}
__device__ __forceinline__ void gld16(const void* g, void* l) {
  __builtin_amdgcn_global_load_lds(
      (const __attribute__((address_space(1))) void*)g,
      (__attribute__((address_space(3))) void*)l, 16, 0, 0);
}

// ---------------- x -> bf16, sigma k-order ----------------
__global__ __launch_bounds__(256) void cvt_bf16_kernel(const float* __restrict__ in,
                                                       unsigned short* __restrict__ out,
                                                       int n16) {
  int i = blockIdx.x * 256 + threadIdx.x;
  if (i >= n16) return;
  const float4* p = (const float4*)(in + (size_t)i * 16);
  float4 a = p[0], b = p[1], c = p[2], d = p[3];
  s16x8 r0, r1;
  r0[0] = (short)f2b(a.x); r0[1] = (short)f2b(a.y); r0[2] = (short)f2b(a.z); r0[3] = (short)f2b(a.w);
  r0[4] = (short)f2b(c.x); r0[5] = (short)f2b(c.y); r0[6] = (short)f2b(c.z); r0[7] = (short)f2b(c.w);
  r1[0] = (short)f2b(b.x); r1[1] = (short)f2b(b.y); r1[2] = (short)f2b(b.z); r1[3] = (short)f2b(b.w);
  r1[4] = (short)f2b(d.x); r1[5] = (short)f2b(d.y); r1[6] = (short)f2b(d.z); r1[7] = (short)f2b(d.w);
  *(s16x8*)(out + (size_t)i * 16) = r0;
  *(s16x8*)(out + (size_t)i * 16 + 8) = r1;
}

// ---------------- W [K][N] f32 -> WT [N][K] bf16, sigma k-order ----------------
__global__ __launch_bounds__(256) void transpose_cvt_kernel(const float* __restrict__ W,
                                                            unsigned short* __restrict__ WT,
                                                            int K, int N) {
  __shared__ float tile[32][33];
  int n0 = blockIdx.x * 32, k0 = blockIdx.y * 32;
  int tx = threadIdx.x, ty = threadIdx.y;
#pragma unroll
  for (int i = 0; i < 4; i++)
    tile[ty + i * 8][tx] = W[(size_t)(k0 + ty + i * 8) * N + n0 + tx];
  __syncthreads();
  int stx = (tx & 19) | ((tx & 4) << 1) | ((tx & 8) >> 1);  // swap bits 2,3
#pragma unroll
  for (int i = 0; i < 4; i++)
    WT[(size_t)(n0 + ty + i * 8) * K + k0 + stx] = f2b(tile[tx][ty + i * 8]);
}

// ---------------- fused qkv GEMM (r10): [8192,1152] @ [3456,1152]^T ----------------
// vt blocks (bcol>=2304) route C through an LDS [128][264] transpose -> coalesced stores.
__global__ __launch_bounds__(256) void gemm_qkv_kernel(const unsigned short* __restrict__ A,
                                                       const unsigned short* __restrict__ BT,
                                                       const float* __restrict__ biasq,
                                                       const float* __restrict__ biaskv,
                                                       unsigned short* __restrict__ qn,
                                                       unsigned short* __restrict__ kn,
                                                       unsigned short* __restrict__ vt) {
  constexpr int K = 1152;
  constexpr int NT = K / 32;  // 36
  __shared__ __align__(16) unsigned short LDSU[3 * 8192 + 3 * 4096];  // 72 KB
  unsigned short* As = LDSU;            // 3 bufs x [256 rows][32 k]
  unsigned short* Bs = LDSU + 3 * 8192; // 3 bufs x [128 rows][32 k]
  int tid = threadIdx.x;
  int lane = tid & 63, wave = tid >> 6;
  int wr = (wave >> 1) * 128, wc = (wave & 1) * 64;
  int l31 = lane & 31, lh = lane >> 5;
  int bid = blockIdx.x;
  int xcd = bid & 7;
  int w = bid >> 3;                  // 0..107
  int st = w / 12, inner = w - st * 12;
  int ibx = inner % 3, iby = inner / 3;
  int bx = st * 3 + ibx;             // 0..26
  int by = xcd * 4 + iby;            // 0..31
  int brow = by * 256, bcol = bx * 128;
  const unsigned short* AsrcP[4];
  const unsigned short* BsrcP[2];
  int dstA[4], dstB[2];
#pragma unroll
  for (int i = 0; i < 4; i++) {
    int c = tid + 256 * i;
    int row = c >> 2, j = c & 3;
    AsrcP[i] = A + (size_t)(brow + row) * K + (j ^ ((row >> 1) & 3)) * 8;
    dstA[i] = (wave * 64 + 256 * i) * 8;
  }
#pragma unroll
  for (int i = 0; i < 2; i++) {
    int c = tid + 256 * i;
    int row = c >> 2, j = c & 3;
    BsrcP[i] = BT + (size_t)(bcol + row) * K + (j ^ ((row >> 1) & 3)) * 8;
    dstB[i] = (wave * 64 + 256 * i) * 8;
  }
#define STAGE(KT, BUF)                                           \
  {                                                              \
    int kb = (KT) * 32;                                          \
    gld16(AsrcP[0] + kb, &As[(BUF) * 8192 + dstA[0]]);           \
    gld16(AsrcP[1] + kb, &As[(BUF) * 8192 + dstA[1]]);           \
    gld16(AsrcP[2] + kb, &As[(BUF) * 8192 + dstA[2]]);           \
    gld16(AsrcP[3] + kb, &As[(BUF) * 8192 + dstA[3]]);           \
    gld16(BsrcP[0] + kb, &Bs[(BUF) * 4096 + dstB[0]]);           \
    gld16(BsrcP[1] + kb, &Bs[(BUF) * 4096 + dstB[1]]);           \
  }
  int fr = (l31 >> 1) & 3;
  int slotk[2] = {(lh ^ fr) * 8, ((2 + lh) ^ fr) * 8};
  STAGE(0, 0);
  STAGE(1, 1);
  f32x16 acc[4][2] = {};
  int cur = 0;
  for (int kt = 0; kt < NT; kt++) {
    if (kt < NT - 1)
      asm volatile("s_waitcnt vmcnt(6)\n\ts_barrier" ::: "memory");
    else
      asm volatile("s_waitcnt vmcnt(0)\n\ts_barrier" ::: "memory");
    if (kt + 2 < NT) {
      int nb = (cur == 0) ? 2 : cur - 1;  // (kt+2)%3
      STAGE(kt + 2, nb);
    }
    int ab = cur * 8192, bb = cur * 4096;
#pragma unroll
    for (int kk = 0; kk < 2; kk++) {
      int so = slotk[kk];
      s16x8 af[4], bf[2];
#pragma unroll
      for (int m = 0; m < 4; m++)
        af[m] = *(const s16x8*)&As[ab + (wr + m * 32 + l31) * 32 + so];
#pragma unroll
      for (int n = 0; n < 2; n++)
        bf[n] = *(const s16x8*)&Bs[bb + (wc + n * 32 + l31) * 32 + so];
      __builtin_amdgcn_s_setprio(1);
#pragma unroll
      for (int m = 0; m < 4; m++)
#pragma unroll
        for (int n = 0; n < 2; n++)
          acc[m][n] = __builtin_amdgcn_mfma_f32_32x32x16_bf16(af[m], bf[n], acc[m][n], 0, 0, 0);
      __builtin_amdgcn_s_setprio(0);
    }
    cur = (cur == 2) ? 0 : cur + 1;
  }
#undef STAGE
  if (bcol >= 2304) {
    // ---- vt tile: transpose through LDS, coalesced 16B stores ----
    __syncthreads();  // K-loop LDS reads done
    int c0 = bcol - 2304;
#pragma unroll
    for (int m = 0; m < 4; m++) {
#pragma unroll
      for (int n = 0; n < 2; n++) {
        int col = wc + n * 32 + l31;
        float bias = biaskv[1152 + c0 + col];
#pragma unroll
        for (int reg = 0; reg < 16; reg++) {
          int row = wr + m * 32 + (reg & 3) + 8 * (reg >> 2) + 4 * lh;
          LDSU[col * 264 + row] = f2b(acc[m][n][reg] + bias);
        }
      }
    }
    __syncthreads();
    int t = brow >> 10, sbase = brow & 1023;
#pragma unroll
    for (int i = 0; i < 16; i++) {
      int id = tid + 256 * i;
      int col = id >> 5, rowc = id & 31;
      int c = c0 + col;
      int h = c / 72, d = c - h * 72;
      s16x8 v8 = *(const s16x8*)&LDSU[col * 264 + rowc * 8];
      *(s16x8*)(vt + ((size_t)((t * 16 + h) * 80 + d)) * 1024 + sbase + rowc * 8) = v8;
    }
  } else {
    // ---- qn/kn tile: direct stores ----
#pragma unroll
    for (int m = 0; m < 4; m++) {
#pragma unroll
      for (int n = 0; n < 2; n++) {
        int gcol = bcol + wc + n * 32 + l31;
        float bias = (gcol < 1152) ? biasq[gcol] : biaskv[gcol - 1152];
        int c = (gcol < 1152) ? gcol : gcol - 1152;
        int h = c / 72, d = c - h * 72;
        unsigned short* dst = (gcol < 1152) ? qn : kn;
#pragma unroll
        for (int reg = 0; reg < 16; reg++) {
          int grow = brow + wr + m * 32 + (reg & 3) + 8 * (reg >> 2) + 4 * lh;
          float v = acc[m][n][reg] + bias;
          int t = grow >> 10, s = grow & 1023;
          dst[((size_t)((t * 16 + h) * 1024 + s)) * 96 + d] = f2b(v);
        }
      }
    }
  }
}

// ---------------- out GEMM (r10 structure): C[M,N] = A[M,K] @ BT[N,K]^T, f32 out ----------------
__global__ __launch_bounds__(256) void gemm_out_kernel(const unsigned short* __restrict__ A,
                                                       const unsigned short* __restrict__ BT,
                                                       int N, int gx,
                                                       float* __restrict__ outF) {
  constexpr int K = 1152;
  constexpr int NT = K / 32;
  __shared__ __align__(16) unsigned short As[3 * 4096];
  __shared__ __align__(16) unsigned short Bs[3 * 4096];
  int tid = threadIdx.x;
  int lane = tid & 63, wave = tid >> 6;
  int wr = (wave >> 1) * 64, wc = (wave & 1) * 64;
  int l31 = lane & 31, lh = lane >> 5;
  int bid = blockIdx.x;
  int xcd = bid & 7;
  int w = bid >> 3;
  int st = w / 24, inner = w - st * 24;
  int ibx = inner % 3, iby = inner / 3;
  int bx = st * 3 + ibx;
  int by = xcd * 8 + iby;
  int brow = by * 128, bcol = bx * 128;
  const unsigned short* AsrcP[2];
  const unsigned short* BsrcP[2];
  int dst0[2];
#pragma unroll
  for (int i = 0; i < 2; i++) {
    int c = tid + 256 * i;
    int row = c >> 2, j = c & 3;
    int ch = j ^ ((row >> 1) & 3);
    AsrcP[i] = A + (size_t)(brow + row) * K + ch * 8;
    BsrcP[i] = BT + (size_t)(bcol + row) * K + ch * 8;
    dst0[i] = (wave * 64 + 256 * i) * 8;
  }
#define STAGE(KT, BUF)                                          \
  {                                                             \
    int kb = (KT) * 32;                                         \
    gld16(AsrcP[0] + kb, &As[(BUF) * 4096 + dst0[0]]);          \
    gld16(BsrcP[0] + kb, &Bs[(BUF) * 4096 + dst0[0]]);          \
    gld16(AsrcP[1] + kb, &As[(BUF) * 4096 + dst0[1]]);          \
    gld16(BsrcP[1] + kb, &Bs[(BUF) * 4096 + dst0[1]]);          \
  }
  int fr = (l31 >> 1) & 3;
  int slotk[2] = {(lh ^ fr) * 8, ((2 + lh) ^ fr) * 8};
  STAGE(0, 0);
  STAGE(1, 1);
  f32x16 acc[2][2] = {};
  int cur = 0;
  for (int kt = 0; kt < NT; kt++) {
    if (kt < NT - 1)
      asm volatile("s_waitcnt vmcnt(4)\n\ts_barrier" ::: "memory");
    else
      asm volatile("s_waitcnt vmcnt(0)\n\ts_barrier" ::: "memory");
    if (kt + 2 < NT) {
      int nb = (cur == 0) ? 2 : cur - 1;
      STAGE(kt + 2, nb);
    }
    int ab = cur * 4096;
#pragma unroll
    for (int kk = 0; kk < 2; kk++) {
      int so = slotk[kk];
      s16x8 af[2], bf[2];
#pragma unroll
      for (int m = 0; m < 2; m++)
        af[m] = *(const s16x8*)&As[ab + (wr + m * 32 + l31) * 32 + so];
#pragma unroll
      for (int n = 0; n < 2; n++)
        bf[n] = *(const s16x8*)&Bs[ab + (wc + n * 32 + l31) * 32 + so];
      __builtin_amdgcn_s_setprio(1);
#pragma unroll
      for (int m = 0; m < 2; m++)
#pragma unroll
        for (int n = 0; n < 2; n++)
          acc[m][n] = __builtin_amdgcn_mfma_f32_32x32x16_bf16(af[m], bf[n], acc[m][n], 0, 0, 0);
      __builtin_amdgcn_s_setprio(0);
    }
    cur = (cur == 2) ? 0 : cur + 1;
  }
#undef STAGE
#pragma unroll
  for (int m = 0; m < 2; m++) {
#pragma unroll
    for (int n = 0; n < 2; n++) {
#pragma unroll
      for (int reg = 0; reg < 16; reg++) {
        int grow = brow + wr + m * 32 + (reg & 3) + 8 * (reg >> 2) + 4 * lh;
        int gcol = bcol + wc + n * 32 + l31;
        outF[(size_t)grow * N + gcol] = acc[m][n][reg];
      }
    }
  }
}

// ---------------- fused per-(row,head) RMSNorm for q and k, zero-fills pads ----------------
__global__ __launch_bounds__(256) void rmsnorm2_kernel(unsigned short* __restrict__ qn,
                                                       unsigned short* __restrict__ kn,
                                                       const float* __restrict__ qg,
                                                       const float* __restrict__ kg) {
  int r = blockIdx.x * 4 + (threadIdx.x >> 6);
  int isK = r >= 131072;
  int g = isK ? r - 131072 : r;
  unsigned short* buf = isK ? kn : qn;
  const float* gamma = isK ? kg : qg;
  int h = (g >> 10) & 15;
  size_t base = (size_t)g * 96;
  int l = threadIdx.x & 63;
  float e0 = b2f(buf[base + l]);
  float e1 = 0.f;
  if (l < 8) e1 = b2f(buf[base + 64 + l]);
  float ss = e0 * e0 + e1 * e1;
#pragma unroll
  for (int m = 1; m < 64; m <<= 1) ss += __shfl_xor(ss, m);
  float sc = rsqrtf(ss * (1.0f / 72.0f) + 1e-6f);
  buf[base + l] = f2b(e0 * sc * gamma[h * 72 + l]);
  if (l < 32) {
    float v = 0.f;
    if (l < 8) v = e1 * sc * gamma[h * 72 + 64 + l];
    buf[base + 64 + l] = f2b(v);
  }
}

// ---------------- flash attention: 128 q-rows/block, fused-QK both groups,
//                  SM/PV pipelined, cvt_pk P-conversion ----------------
__global__ __launch_bounds__(256) void attn_kernel(const unsigned short* __restrict__ Qn,
                                                   const unsigned short* __restrict__ Kn,
                                                   const unsigned short* __restrict__ VtG,
                                                   unsigned short* __restrict__ att) {
  __shared__ unsigned short Kl[2][64][100];
  __shared__ unsigned short Vt[2][80][76];
  int tid = threadIdx.x;
  int lane = tid & 63, wave = tid >> 6;
  int l15 = lane & 15, lq = lane >> 4, kf = lq * 4;
  int bid = blockIdx.x;
  int orig = (bid & 7) * 128 + (bid >> 3);
  int qb = orig & 7, th = orig >> 3;
  int t = th >> 4, h = th & 15;
  const unsigned short* Q = Qn + (size_t)th * 1024 * 96;
  const unsigned short* Kp = Kn + (size_t)th * 1024 * 96;
  const unsigned short* Vg = VtG + (size_t)th * 80 * 1024;
  int qrow0 = qb * 128 + wave * 32;
  int krow[3], kco[3], vd[3], vco[3];
#pragma unroll
  for (int i = 0; i < 3; i++) {
    int c = tid + i * 256;
    krow[i] = c / 12;
    kco[i] = c - 12 * krow[i];
    int cc = tid + i * 256;
    vd[i] = cc >> 3;
    vco[i] = cc & 7;
  }
  bool v2 = tid < 128;
  s16x8 sk[3], sv[3];
  s16x8 qf0[3], qf1[3];
#pragma unroll
  for (int c = 0; c < 3; c++) {
    const unsigned short* p0 = Q + (size_t)(qrow0 + l15) * 96 + c * 32 + kf;
    s16x4 lo = *(const s16x4*)p0;
    s16x4 hi = *(const s16x4*)(p0 + 16);
    qf0[c] = __builtin_shufflevector(lo, hi, 0, 1, 2, 3, 4, 5, 6, 7);
    const unsigned short* p1 = Q + (size_t)(qrow0 + 16 + l15) * 96 + c * 32 + kf;
    s16x4 lo1 = *(const s16x4*)p1;
    s16x4 hi1 = *(const s16x4*)(p1 + 16);
    qf1[c] = __builtin_shufflevector(lo1, hi1, 0, 1, 2, 3, 4, 5, 6, 7);
  }
  f32x4 o[2][5] = {};
  float m_r[2] = {-3.0e38f, -3.0e38f}, l_r[2] = {0.f, 0.f};

#pragma unroll
  for (int i = 0; i < 3; i++)
    sk[i] = *(const s16x8*)(Kp + (size_t)krow[i] * 96 + kco[i] * 8);
#pragma unroll
  for (int i = 0; i < 2; i++)
    sv[i] = *(const s16x8*)(Vg + (size_t)vd[i] * 1024 + vco[i] * 8);
  if (v2) sv[2] = *(const s16x8*)(Vg + (size_t)vd[2] * 1024 + vco[2] * 8);
#pragma unroll
  for (int i = 0; i < 3; i++) *(s16x8*)&Kl[0][krow[i]][kco[i] * 8] = sk[i];
#pragma unroll
  for (int i = 0; i < 2; i++) *(s16x8*)&Vt[0][vd[i]][vco[i] * 8] = sv[i];
  if (v2) *(s16x8*)&Vt[0][vd[2]][vco[2] * 8] = sv[2];

  for (int tt = 0; tt < 16; tt++) {
    __syncthreads();
    int cur = tt & 1;
    if (tt < 15) {
      int kv1 = (tt + 1) * 64;
#pragma unroll
      for (int i = 0; i < 3; i++)
        sk[i] = *(const s16x8*)(Kp + (size_t)(kv1 + krow[i]) * 96 + kco[i] * 8);
#pragma unroll
      for (int i = 0; i < 2; i++)
        sv[i] = *(const s16x8*)(Vg + (size_t)vd[i] * 1024 + kv1 + vco[i] * 8);
      if (v2) sv[2] = *(const s16x8*)(Vg + (size_t)vd[2] * 1024 + kv1 + vco[2] * 8);
    }
    // ---- QK^T for BOTH groups, sharing K-fragment reads ----
    f32x4 st0[4], st1[4];
    __builtin_amdgcn_s_setprio(1);
#pragma unroll
    for (int n = 0; n < 4; n++) {
      f32x4 a0 = {}, a1 = {};
#pragma unroll
      for (int c = 0; c < 3; c++) {
        s16x4 lo = *(const s16x4*)&Kl[cur][n * 16 + l15][c * 32 + kf];
        s16x4 hi = *(const s16x4*)&Kl[cur][n * 16 + l15][c * 32 + kf + 16];
        s16x8 kfr = __builtin_shufflevector(lo, hi, 0, 1, 2, 3, 4, 5, 6, 7);
        a0 = __builtin_amdgcn_mfma_f32_16x16x32_bf16(kfr, qf0[c], a0, 0, 0, 0);
        a1 = __builtin_amdgcn_mfma_f32_16x16x32_bf16(kfr, qf1[c], a1, 0, 0, 0);
      }
      st0[n] = a0;
      st1[n] = a1;
    }
    __builtin_amdgcn_s_setprio(0);
#define SOFTMAX(ST, G)                                                        \
    {                                                                         \
      float tmax = ST[0][0];                                                  \
      _Pragma("unroll") for (int n = 0; n < 4; n++)                           \
        _Pragma("unroll") for (int r = 0; r < 4; r++)                         \
          tmax = fmaxf(tmax, ST[n][r]);                                       \
      tmax = fmaxf(tmax, __shfl_xor(tmax, 16));                               \
      tmax = fmaxf(tmax, __shfl_xor(tmax, 32));                               \
      float mn = fmaxf(m_r[G], tmax);                                         \
      float scale = __expf(m_r[G] - mn);                                      \
      m_r[G] = mn;                                                            \
      float sum = 0.f;                                                        \
      _Pragma("unroll") for (int n = 0; n < 4; n++)                           \
        _Pragma("unroll") for (int r = 0; r < 4; r++) {                       \
          float p = __expf(ST[n][r] - mn);                                    \
          ST[n][r] = p;                                                       \
          sum += p;                                                           \
        }                                                                     \
      sum += __shfl_xor(sum, 16);                                             \
      sum += __shfl_xor(sum, 32);                                             \
      l_r[G] = l_r[G] * scale + sum;                                          \
      _Pragma("unroll") for (int r = 0; r < 4; r++) {                         \
        float scq = __shfl(scale, 4 * lq + r);                                \
        _Pragma("unroll") for (int v = 0; v < 5; v++) o[G][v][r] *= scq;      \
      }                                                                       \
    }
    // P fragment via v_cvt_pk_bf16_f32 (RNE, = f2b): u32[i] packs adjacent k-pairs.
#define PV(ST, G)                                                             \
    {                                                                         \
      __builtin_amdgcn_s_setprio(1);                                          \
      _Pragma("unroll") for (int b = 0; b < 2; b++) {                         \
        int w0, w1, w2, w3;                                                   \
        asm("v_cvt_pk_bf16_f32 %0, %1, %2" : "=v"(w0)                         \
            : "v"(ST[2 * b][0]), "v"(ST[2 * b][1]));                          \
        asm("v_cvt_pk_bf16_f32 %0, %1, %2" : "=v"(w1)                         \
            : "v"(ST[2 * b][2]), "v"(ST[2 * b][3]));                          \
        asm("v_cvt_pk_bf16_f32 %0, %1, %2" : "=v"(w2)                         \
            : "v"(ST[2 * b + 1][0]), "v"(ST[2 * b + 1][1]));                  \
        asm("v_cvt_pk_bf16_f32 %0, %1, %2" : "=v"(w3)                         \
            : "v"(ST[2 * b + 1][2]), "v"(ST[2 * b + 1][3]));                  \
        i32x4 pw = {w0, w1, w2, w3};                                          \
        s16x8 pf = __builtin_bit_cast(s16x8, pw);                             \
        _Pragma("unroll") for (int v = 0; v < 5; v++) {                       \
          s16x4 vlo = *(const s16x4*)&Vt[cur][v * 16 + l15][b * 32 + kf];     \
          s16x4 vhi = *(const s16x4*)&Vt[cur][v * 16 + l15][b * 32 + kf + 16];\
          s16x8 vf = __builtin_shufflevector(vlo, vhi, 0, 1, 2, 3, 4, 5, 6, 7);\
          o[G][v] = __builtin_amdgcn_mfma_f32_16x16x32_bf16(pf, vf, o[G][v], 0, 0, 0); \
        }                                                                     \
      }                                                                       \
      __builtin_amdgcn_s_setprio(0);                                          \
    }
    SOFTMAX(st0, 0);
    PV(st0, 0);       // PV0 MFMAs overlap SM1's VALU below
    SOFTMAX(st1, 1);
    PV(st1, 1);
#undef SOFTMAX
#undef PV
    if (tt < 15) {
      int nxt = cur ^ 1;
#pragma unroll
      for (int i = 0; i < 3; i++) *(s16x8*)&Kl[nxt][krow[i]][kco[i] * 8] = sk[i];
#pragma unroll
      for (int i = 0; i < 2; i++) *(s16x8*)&Vt[nxt][vd[i]][vco[i] * 8] = sv[i];
      if (v2) *(s16x8*)&Vt[nxt][vd[2]][vco[2] * 8] = sv[2];
    }
  }
  // epilogue: normalize by l, store d<72 at sigma-permuted column
#pragma unroll
  for (int g = 0; g < 2; g++)
#pragma unroll
    for (int r = 0; r < 4; r++) {
      float inv = 1.0f / __shfl(l_r[g], 4 * lq + r);
      int qrow = qrow0 + g * 16 + 4 * lq + r;
      size_t rowbase = (size_t)(t * 1024 + qrow) * 1152;
#pragma unroll
      for (int v = 0; v < 5; v++) {
        int d = v * 16 + l15;
        if (d < 72) {
          int col = h * 72 + d;
          int scol = (col & ~12) | ((col & 4) << 1) | ((col & 8) >> 1);
          att[rowbase + scol] = f2b(o[g][v][r] * inv);
        }
      }
    }
}

extern "C" void kernel_launch(void* const* d_in, const int* in_sizes, int n_in,
                              void* d_out, int out_size, void* d_ws, size_t ws_size,
                              hipStream_t stream) {
  const float* x   = (const float*)d_in[0];
  const float* Wq  = (const float*)d_in[1];
  const float* bq  = (const float*)d_in[2];
  const float* Wkv = (const float*)d_in[3];
  const float* bkv = (const float*)d_in[4];
  const float* qg  = (const float*)d_in[5];
  const float* kg  = (const float*)d_in[6];
  const float* Wo  = (const float*)d_in[7];
  float* out = (float*)d_out;

  char* w = (char*)d_ws;
  unsigned short* xb   = (unsigned short*)w; w += (size_t)8192 * 1152 * 2;
  unsigned short* WqT  = (unsigned short*)w; w += (size_t)1152 * 1152 * 2;  // contiguous with WkvT
  unsigned short* WkvT = (unsigned short*)w; w += (size_t)2304 * 1152 * 2;
  unsigned short* WoT  = (unsigned short*)w; w += (size_t)1152 * 1152 * 2;
  unsigned short* qn   = (unsigned short*)w; w += (size_t)128 * 1024 * 96 * 2;
  unsigned short* kn   = (unsigned short*)w; w += (size_t)128 * 1024 * 96 * 2;
  unsigned short* vt   = (unsigned short*)w; w += (size_t)128 * 80 * 1024 * 2;
  unsigned short* att  = (unsigned short*)w; w += (size_t)8192 * 1152 * 2;

  cvt_bf16_kernel<<<2304, 256, 0, stream>>>(x, xb, 9437184 / 16);
  transpose_cvt_kernel<<<dim3(36, 36), dim3(32, 8), 0, stream>>>(Wq, WqT, 1152, 1152);
  transpose_cvt_kernel<<<dim3(72, 36), dim3(32, 8), 0, stream>>>(Wkv, WkvT, 1152, 2304);
  transpose_cvt_kernel<<<dim3(36, 36), dim3(32, 8), 0, stream>>>(Wo, WoT, 1152, 1152);

  // fused q,k,v^T GEMM: BT = [WqT ; WkvT] = [3456][1152], grid 32*27=864
  gemm_qkv_kernel<<<864, 256, 0, stream>>>(xb, WqT, bq, bkv, qn, kn, vt);
  rmsnorm2_kernel<<<65536, 256, 0, stream>>>(qn, kn, qg, kg);

  attn_kernel<<<1024, 256, 0, stream>>>(qn, kn, vt, att);

  // out = att @ WoT^T, grid 9*64=576
  gemm_out_kernel<<<576, 256, 0, stream>>>(att, WoT, 1152, 9, out);
}